// Round 4
// baseline (689.943 us; speedup 1.0000x reference)
//
#include <hip/hip_runtime.h>
#include <hip/hip_bf16.h>
#include <math.h>

// ---- config (mirrors reference) ----
#define BB 2
#define LL 2048
#define DM 512
#define DK 64
#define NH 8
#define RK 32
#define RFF 128
#define KMAX 64
#define BL (BB*LL)            // 4096
#define NQ (NH*BB*LL)         // 32768 query-head rows
#define NCH 16                // chunks per (b,g) row for bucket build
#define CHW (LL/NCH)          // 128 keys per chunk

#define RFF_SCALE 0.125f                   /* sqrt(2/128) */
#define INV_SQRT_RFF 0.08838834764831845f  /* 1/sqrt(128) */

typedef unsigned long long u64;

// exact per-byte zero detect: 0x80 bit set iff that byte of x is zero
__device__ __forceinline__ unsigned int zbytes(unsigned int x) {
  return ~(((x & 0x7F7F7F7Fu) + 0x7F7F7F7Fu) | x | 0x7F7F7F7Fu);
}
__device__ __forceinline__ u64 zbytes64(u64 x) {
  return ~(((x & 0x7F7F7F7F7F7F7F7Full) + 0x7F7F7F7F7F7F7F7Full) | x | 0x7F7F7F7F7F7F7F7Full);
}

// ================= K1: down projections, 16 rows/block, fused k-codes ==============
// grid (BL/16, 3), block 256. which: 0=q 1=k 2=v.
__global__ __launch_bounds__(256) void k_down_proj(
    const float* __restrict__ q, const float* __restrict__ k, const float* __restrict__ v,
    const float* __restrict__ Wq, const float* __restrict__ bq,
    const float* __restrict__ Wkv, const float* __restrict__ bkv,
    float* __restrict__ qd, float* __restrict__ kd, float* __restrict__ vd,
    unsigned char* __restrict__ kcodes, u64* __restrict__ kcodes8) {
  int r0 = blockIdx.x * 16;
  int which = blockIdx.y;
  const float* src = (which == 0) ? q : (which == 1) ? k : v;
  const float* W   = (which == 0) ? Wq : Wkv;
  const float* bias= (which == 0) ? bq : bkv;
  float* dst       = (which == 0) ? qd : (which == 1) ? kd : vd;
  int tid = threadIdx.x;
  int d = tid & 63, rg = tid >> 6;

  __shared__ float sin_[16][DM];     // 32KB
  const float4* s4 = (const float4*)(src + (size_t)r0 * DM);
  float4* l4 = (float4*)&sin_[0][0];
  #pragma unroll
  for (int u = 0; u < 8; ++u) l4[tid + u * 256] = s4[tid + u * 256];
  __syncthreads();

  float acc[4] = {0.f, 0.f, 0.f, 0.f};
  for (int t4 = 0; t4 < DM / 4; ++t4) {
    float w[4];
    #pragma unroll
    for (int u = 0; u < 4; ++u) w[u] = W[(t4 * 4 + u) * DK + d];
    #pragma unroll
    for (int r = 0; r < 4; ++r) {
      float4 c4 = *(const float4*)&sin_[rg * 4 + r][t4 * 4];   // wave-broadcast b128
      acc[r] = fmaf(c4.x, w[0], acc[r]);
      acc[r] = fmaf(c4.y, w[1], acc[r]);
      acc[r] = fmaf(c4.z, w[2], acc[r]);
      acc[r] = fmaf(c4.w, w[3], acc[r]);
    }
  }
  float bs = bias[d];
  #pragma unroll
  for (int r = 0; r < 4; ++r) {
    int R = r0 + rg * 4 + r;
    float val = acc[r] + bs;
    dst[(size_t)R * DK + d] = val;
    if (which == 1) {
      u64 m = __ballot(val > 0.f);   // bit d = sign of feature d; byte g = code of group g
      int b = R >> 11, j = R & 2047;
      if (d == 0) kcodes8[((size_t)b << 11) + j] = m;
      if (d < 8)
        kcodes[(((size_t)b * 8 + d) << 11) + j] = (unsigned char)((m >> (8 * d)) & 0xFF);
    }
  }
}

// ===== K2: per-head precompute W_absorb (TRANSPOSED) and Wv = u_v@v_v =====
__global__ __launch_bounds__(256) void k_head_pre(
    const float* __restrict__ u_q, const float* __restrict__ v_q,
    const float* __restrict__ u_k, const float* __restrict__ v_k,
    const float* __restrict__ u_v, const float* __restrict__ v_v,
    float* __restrict__ WabsT, float* __restrict__ Wv) {
  int h = blockIdx.x, tid = threadIdx.x;
  __shared__ float sU[DK * RK];
  __shared__ float sV[RK * DK];
  __shared__ float sWUQ[DK * DK];
  __shared__ float sWUK[DK * DK];
  for (int e = tid; e < DK * RK; e += 256) sU[e] = u_q[h * DK * RK + e];
  for (int e = tid; e < RK * DK; e += 256) sV[e] = v_q[h * RK * DK + e];
  __syncthreads();
  for (int e = tid; e < DK * DK; e += 256) {
    int r = e >> 6, c = e & 63;
    float a = 0.f;
    for (int t = 0; t < RK; ++t) a = fmaf(sU[r * RK + t], sV[t * DK + c], a);
    sWUQ[e] = a;
  }
  __syncthreads();
  for (int e = tid; e < DK * RK; e += 256) sU[e] = u_k[h * DK * RK + e];
  for (int e = tid; e < RK * DK; e += 256) sV[e] = v_k[h * RK * DK + e];
  __syncthreads();
  for (int e = tid; e < DK * DK; e += 256) {
    int r = e >> 6, c = e & 63;
    float a = 0.f;
    for (int t = 0; t < RK; ++t) a = fmaf(sU[r * RK + t], sV[t * DK + c], a);
    sWUK[e] = a;
  }
  __syncthreads();
  for (int e = tid; e < DK * DK; e += 256) {
    int a_ = e >> 6, q_ = e & 63;
    float a = 0.f;
    for (int c = 0; c < DK; ++c) a = fmaf(sWUK[c * DK + a_], sWUQ[c * DK + q_], a);
    WabsT[h * DK * DK + q_ * DK + a_] = a;
  }
  __syncthreads();
  for (int e = tid; e < DK * RK; e += 256) sU[e] = u_v[h * DK * RK + e];
  __syncthreads();
  const float* vv = v_v + (size_t)h * RK * DM;
  for (int e = tid; e < DK * DM; e += 256) {
    int d = e >> 9, o = e & 511;
    float a = 0.f;
    for (int c = 0; c < RK; ++c) a = fmaf(sU[d * RK + c], vv[c * DM + o], a);
    Wv[(size_t)h * DK * DM + e] = a;
  }
}

// ===== K3: M2 = Wv @ W_out (per-head slice), 8 rows/block. grid (NH, 8) =====
__global__ __launch_bounds__(256) void k_m2(
    const float* __restrict__ Wv, const float* __restrict__ W_out, float* __restrict__ M2) {
  int h = blockIdx.x, d0 = blockIdx.y * 8;
  int tid = threadIdx.x;
  __shared__ float4 sWv4[8][DM / 4];
  const float4* g4 = (const float4*)(Wv + ((size_t)h * DK + d0) * DM);
  float4* l4 = &sWv4[0][0];
  #pragma unroll
  for (int u = 0; u < 4; ++u) l4[tid + u * 256] = g4[tid + u * 256];
  __syncthreads();
  float a0[8], a1[8];
  #pragma unroll
  for (int r = 0; r < 8; ++r) { a0[r] = 0.f; a1[r] = 0.f; }
  const float* Wo = W_out + (size_t)h * DM * DM;
  for (int p4 = 0; p4 < DM / 4; ++p4) {
    float m0[4], m1[4];
    #pragma unroll
    for (int u = 0; u < 4; ++u) {
      m0[u] = Wo[(size_t)(p4 * 4 + u) * DM + tid];
      m1[u] = Wo[(size_t)(p4 * 4 + u) * DM + tid + 256];
    }
    #pragma unroll
    for (int r = 0; r < 8; ++r) {
      float4 c4 = sWv4[r][p4];
      a0[r] = fmaf(c4.x, m0[0], a0[r]); a0[r] = fmaf(c4.y, m0[1], a0[r]);
      a0[r] = fmaf(c4.z, m0[2], a0[r]); a0[r] = fmaf(c4.w, m0[3], a0[r]);
      a1[r] = fmaf(c4.x, m1[0], a1[r]); a1[r] = fmaf(c4.y, m1[1], a1[r]);
      a1[r] = fmaf(c4.z, m1[2], a1[r]); a1[r] = fmaf(c4.w, m1[3], a1[r]);
    }
  }
  #pragma unroll
  for (int r = 0; r < 8; ++r) {
    size_t row = (size_t)h * DK + d0 + r;
    M2[row * DM + tid] = a0[r];
    M2[row * DM + tid + 256] = a1[r];
  }
}

// ===== K4: fused phi_q (+q-codes via ballot) / phi_k. grid (BL/16, NH, 2) =====
__global__ __launch_bounds__(256, 4) void k_phi(
    const float* __restrict__ qd, const float* __restrict__ kd,
    const float* __restrict__ WabsT,
    const float* __restrict__ omega, const float* __restrict__ rff_bias,
    float* __restrict__ phiq, float* __restrict__ phik,
    u64* __restrict__ qcodes8) {
  int r0 = blockIdx.x * 16;
  int h = blockIdx.y;
  int isK = blockIdx.z;
  int tid = threadIdx.x;
  __shared__ float sq[16][DK];
  __shared__ float qp[16][DK];

  if (!isK) {
    const float4* g4 = (const float4*)(qd + (size_t)r0 * DK);
    float4* l4 = (float4*)&sq[0][0];
    l4[tid] = g4[tid];
    __syncthreads();
    int a_ = tid & 63, rg = tid >> 6;
    float acc[4] = {0.f, 0.f, 0.f, 0.f};
    const float* Wt = WabsT + h * DK * DK;
    for (int t = 0; t < DK; ++t) {
      float w = Wt[t * DK + a_];
      #pragma unroll
      for (int r = 0; r < 4; ++r) acc[r] = fmaf(sq[rg * 4 + r][t], w, acc[r]);
    }
    #pragma unroll
    for (int r = 0; r < 4; ++r) {
      u64 m = __ballot(acc[r] > 0.f);       // bit a_ = sign of Qp dim a_
      int R = r0 + rg * 4 + r;
      if (a_ == 0) {
        int b = R >> 11, i = R & 2047;
        qcodes8[(((size_t)h * BB + b) << 11) + i] = m;
      }
      qp[R - r0][a_] = acc[r];
    }
    __syncthreads();
  } else {
    const float4* g4 = (const float4*)(kd + (size_t)r0 * DK);
    float4* l4 = (float4*)&qp[0][0];
    l4[tid] = g4[tid];
    __syncthreads();
  }

  int col = tid & 127, rg2 = tid >> 7;
  float acc[8];
  float bias = rff_bias[h * RFF + col];
  #pragma unroll
  for (int r = 0; r < 8; ++r) acc[r] = bias;
  const float* om = omega + (size_t)h * DK * RFF;
  #pragma unroll 4
  for (int d4 = 0; d4 < DK / 4; ++d4) {
    float w[4];
    #pragma unroll
    for (int u = 0; u < 4; ++u) w[u] = om[(size_t)(d4 * 4 + u) * RFF + col];
    #pragma unroll
    for (int r = 0; r < 8; ++r) {
      float4 c4 = *(const float4*)&qp[rg2 * 8 + r][d4 * 4];
      acc[r] = fmaf(c4.x, w[0], acc[r]); acc[r] = fmaf(c4.y, w[1], acc[r]);
      acc[r] = fmaf(c4.z, w[2], acc[r]); acc[r] = fmaf(c4.w, w[3], acc[r]);
    }
  }
  float* dst = isK ? phik : phiq;
  #pragma unroll
  for (int r = 0; r < 8; ++r) {
    int R = r0 + rg2 * 8 + r;
    dst[((size_t)h * BL + R) * RFF + col] = cosf(acc[r]) * RFF_SCALE;
  }
}

// ===== K5a: per-chunk histogram. grid (16 bg, 16 ch), block 256 (thread = code) =====
__global__ __launch_bounds__(256) void k_bhist(
    const unsigned char* __restrict__ kcodes, int* __restrict__ chist) {
  int bg = blockIdx.x, ch = blockIdx.y;
  int c = threadIdx.x;
  __shared__ unsigned int wrd[CHW / 4];
  if (c < CHW / 4)
    wrd[c] = ((const unsigned int*)(kcodes + (size_t)bg * LL + ch * CHW))[c];
  __syncthreads();
  unsigned int pat = (unsigned)c * 0x01010101u;
  int cnt = 0;
  #pragma unroll
  for (int t = 0; t < CHW / 4; ++t)
    cnt += __popc(zbytes(wrd[t] ^ pat));
  chist[((size_t)bg * NCH + ch) * 256 + c] = cnt;
}

// ===== K5b: exclusive scan over chunks (in-place). grid 16, block 256 =====
__global__ __launch_bounds__(256) void k_bscan(int* __restrict__ chist) {
  int bg = blockIdx.x, c = threadIdx.x;
  int base = 0;
  #pragma unroll
  for (int ch = 0; ch < NCH; ++ch) {
    size_t idx = ((size_t)bg * NCH + ch) * 256 + c;
    int v = chist[idx];
    chist[idx] = base;
    base += v;
  }
}

// ===== K5c: per-key in-bucket rank (byte g of krank8[b][j]). grid (16,16) =====
__global__ __launch_bounds__(256) void k_brank(
    const unsigned char* __restrict__ kcodes, const int* __restrict__ chist,
    unsigned char* __restrict__ krankb) {
  int bg = blockIdx.x, ch = blockIdx.y;
  int c = threadIdx.x;
  __shared__ unsigned int wrd[CHW / 4];
  if (c < CHW / 4)
    wrd[c] = ((const unsigned int*)(kcodes + (size_t)bg * LL + ch * CHW))[c];
  __syncthreads();
  int pos = chist[((size_t)bg * NCH + ch) * 256 + c];
  unsigned int pat = (unsigned)c * 0x01010101u;
  int b = bg >> 3, g = bg & 7;
  int j0 = ch * CHW;
  for (int t = 0; t < CHW / 4; ++t) {
    unsigned int zm = zbytes(wrd[t] ^ pat);
    while (zm) {
      int byte = (__ffs(zm) - 1) >> 3;
      int j = j0 + t * 4 + byte;
      krankb[((((size_t)b << 11) + j) << 3) + g] = (unsigned char)(pos > 254 ? 254 : pos);
      ++pos;
      zm &= zm - 1;
    }
  }
}

// ===== K6: candidates via wave-per-query ballot scan (no LDS, no bitmap) =====
// grid NQ/4, block 256 (4 waves). Candidate j iff exists g: code match && rank<64.
__global__ __launch_bounds__(256) void k_cand(
    const u64* __restrict__ qcodes8, const u64* __restrict__ kcodes8,
    const u64* __restrict__ krank8, int* __restrict__ cand, int* __restrict__ nval) {
  int lane = threadIdx.x & 63;
  int qidx = blockIdx.x * 4 + (threadIdx.x >> 6);
  int h = qidx >> 12;
  int b = (qidx >> 11) & 1;
  int i = qidx & 2047;
  u64 qc = qcodes8[(((size_t)h * BB + b) << 11) + i];   // wave-uniform
  const u64* kc8 = kcodes8 + ((size_t)b << 11);
  const u64* kr8 = krank8 + ((size_t)b << 11);
  int* cptr = cand + (size_t)qidx * KMAX;
  int base = 0;
  for (int w = 0; w < LL / 64; ++w) {
    int j = w * 64 + lane;
    u64 x = kc8[j] ^ qc;
    u64 zb = zbytes64(x);                         // 0x80 per matching-code byte
    u64 t = kr8[j] & 0xC0C0C0C0C0C0C0C0ull;       // rank>=64 ⇒ bit6|bit7 set
    u64 tt = (t | (t << 1)) & 0x8080808080808080ull;
    bool is_cand = (zb & ~tt) != 0ull;
    u64 mask = __ballot(is_cand);
    int pos = base + __popcll(mask & ((1ull << lane) - 1ull));
    if (is_cand && pos < KMAX) cptr[pos] = j;
    base += __popcll(mask);
    if (base >= KMAX) break;                      // wave-uniform
  }
  int nv = base < KMAX ? base : KMAX;
  if (lane == 0) nval[qidx] = nv;
  for (int t2 = nv + lane; t2 < KMAX; t2 += 64) cptr[t2] = 0;
}

// ===== K7: scores + softmax + weighted V sum. XCD-chunked swizzle. =====
__global__ __launch_bounds__(256) void k_attn(
    const float* __restrict__ phiq, const float* __restrict__ phik,
    const int* __restrict__ cand, const int* __restrict__ nval,
    const float* __restrict__ vd, float* __restrict__ ctx) {
  __shared__ float lw[4][KMAX];
  __shared__ int   lc[4][KMAX];
  // XCD-chunked swizzle: 8192 blocks -> XCD x owns contiguous work [x*1024,(x+1)*1024)
  // so each XCD's L2 holds one head's phik (2MB) + vd (1MB).
  int swz = (blockIdx.x & 7) * ((NQ / 4) / 8) + (blockIdx.x >> 3);
  int lane = threadIdx.x & 63;
  int wv = threadIdx.x >> 6;
  int qidx = swz * 4 + wv;
  int b = (qidx >> 11) & 1;
  int i = qidx & 2047;
  int base = qidx - i;                 // (h*BB+b)*LL in phi-row space
  int nv = nval[qidx];
  int c = cand[(size_t)qidx * KMAX + lane];
  const float4* pq = (const float4*)(phiq + (size_t)qidx * RFF);
  const float4* pk = (const float4*)(phik + (size_t)(base + c) * RFF);
  float s = 0.f;
  #pragma unroll
  for (int f = 0; f < RFF / 4; ++f) {
    float4 a = pq[f], bb = pk[f];
    s += a.x * bb.x + a.y * bb.y + a.z * bb.z + a.w * bb.w;
  }
  s *= INV_SQRT_RFF;
  bool valid = lane < nv;
  s = valid ? s : -1e30f;
  float m = s;
  #pragma unroll
  for (int off = 32; off >= 1; off >>= 1) m = fmaxf(m, __shfl_xor(m, off));
  float e = expf(s - m);
  float sum = e;
  #pragma unroll
  for (int off = 32; off >= 1; off >>= 1) sum += __shfl_xor(sum, off);
  float w = valid ? (e / sum) : 0.f;
  lw[wv][lane] = w;
  lc[wv][lane] = c;
  __syncthreads();
  float acc = 0.f;
  const float* vb = vd + (size_t)b * LL * DK;
  for (int k4 = 0; k4 < KMAX / 4; ++k4) {
    float4 w4 = *(const float4*)&lw[wv][k4 * 4];
    int4   c4 = *(const int4*)&lc[wv][k4 * 4];
    acc = fmaf(w4.x, vb[(size_t)c4.x * DK + lane], acc);
    acc = fmaf(w4.y, vb[(size_t)c4.y * DK + lane], acc);
    acc = fmaf(w4.z, vb[(size_t)c4.z * DK + lane], acc);
    acc = fmaf(w4.w, vb[(size_t)c4.w * DK + lane], acc);
  }
  int h = qidx >> 12;
  ctx[((size_t)(b * LL + i)) * (NH * DK) + h * DK + lane] = acc;
}

// ===== K8: out = ctx @ M2 + b_out, 16 rows/block. grid BL/16 =====
__global__ __launch_bounds__(256) void k_out(
    const float* __restrict__ ctx, const float* __restrict__ M2,
    const float* __restrict__ b_out, float* __restrict__ out) {
  int r0 = blockIdx.x * 16;
  int tid = threadIdx.x;
  __shared__ float4 sctx4[16][DM / 4];
  const float4* g4 = (const float4*)(ctx + (size_t)r0 * DM);
  float4* l4 = &sctx4[0][0];
  #pragma unroll
  for (int u = 0; u < 8; ++u) l4[tid + u * 256] = g4[tid + u * 256];
  __syncthreads();
  float a0[16], a1[16];
  #pragma unroll
  for (int r = 0; r < 16; ++r) { a0[r] = 0.f; a1[r] = 0.f; }
  for (int p4 = 0; p4 < DM / 4; ++p4) {
    float m0[4], m1[4];
    #pragma unroll
    for (int u = 0; u < 4; ++u) {
      m0[u] = M2[(size_t)(p4 * 4 + u) * DM + tid];
      m1[u] = M2[(size_t)(p4 * 4 + u) * DM + tid + 256];
    }
    #pragma unroll
    for (int r = 0; r < 16; ++r) {
      float4 c4 = sctx4[r][p4];
      a0[r] = fmaf(c4.x, m0[0], a0[r]); a0[r] = fmaf(c4.y, m0[1], a0[r]);
      a0[r] = fmaf(c4.z, m0[2], a0[r]); a0[r] = fmaf(c4.w, m0[3], a0[r]);
      a1[r] = fmaf(c4.x, m1[0], a1[r]); a1[r] = fmaf(c4.y, m1[1], a1[r]);
      a1[r] = fmaf(c4.z, m1[2], a1[r]); a1[r] = fmaf(c4.w, m1[3], a1[r]);
    }
  }
  float b0 = b_out[tid], b1 = b_out[tid + 256];
  #pragma unroll
  for (int r = 0; r < 16; ++r) {
    out[(size_t)(r0 + r) * DM + tid] = a0[r] + b0;
    out[(size_t)(r0 + r) * DM + tid + 256] = a1[r] + b1;
  }
}

extern "C" void kernel_launch(void* const* d_in, const int* in_sizes, int n_in,
                              void* d_out, int out_size, void* d_ws, size_t ws_size,
                              hipStream_t stream) {
  const float* query = (const float*)d_in[0];
  const float* key   = (const float*)d_in[1];
  const float* value = (const float*)d_in[2];
  const float* Wq    = (const float*)d_in[3];
  const float* bq    = (const float*)d_in[4];
  const float* Wkv   = (const float*)d_in[5];
  const float* bkv   = (const float*)d_in[6];
  const float* u_q   = (const float*)d_in[7];
  const float* v_q   = (const float*)d_in[8];
  const float* u_k   = (const float*)d_in[9];
  const float* v_k   = (const float*)d_in[10];
  const float* u_v   = (const float*)d_in[11];
  const float* v_v   = (const float*)d_in[12];
  const float* omega = (const float*)d_in[13];
  const float* rffb  = (const float*)d_in[14];
  const float* W_out = (const float*)d_in[15];
  const float* b_out = (const float*)d_in[16];
  float* out = (float*)d_out;

  // ---- workspace carve (256B aligned) ----
  size_t off = 0;
  char* ws = (char*)d_ws;
  auto carve = [&](size_t bytes) -> void* {
    void* p = ws + off;
    off += (bytes + 255) & ~(size_t)255;
    return p;
  };
  float* qd    = (float*)carve((size_t)BL * DK * 4);
  float* kd    = (float*)carve((size_t)BL * DK * 4);
  float* vd    = (float*)carve((size_t)BL * DK * 4);
  float* WabsT = (float*)carve((size_t)NH * DK * DK * 4);
  float* Wv    = (float*)carve((size_t)NH * DK * DM * 4);
  float* M2    = (float*)carve((size_t)NH * DK * DM * 4);
  float* phiq  = (float*)carve((size_t)NQ * RFF * 4);
  float* phik  = (float*)carve((size_t)NQ * RFF * 4);
  unsigned char* kcodes = (unsigned char*)carve((size_t)BB * 8 * LL);
  u64* kcodes8 = (u64*)carve((size_t)BB * LL * 8);
  u64* qcodes8 = (u64*)carve((size_t)NH * BB * LL * 8);
  u64* krank8  = (u64*)carve((size_t)BB * LL * 8);
  int* chist = (int*)carve((size_t)BB * 8 * NCH * 256 * 4);
  int* cand  = (int*)carve((size_t)NQ * KMAX * 4);
  int* nval  = (int*)carve((size_t)NQ * 4);
  float* ctx = (float*)carve((size_t)BL * NH * DK * 4);
  (void)ws_size;

  // ---- launches (fixed sequence, all on stream) ----
  k_down_proj<<<dim3(BL / 16, 3), 256, 0, stream>>>(query, key, value, Wq, bq, Wkv, bkv,
                                                    qd, kd, vd, kcodes, kcodes8);
  k_head_pre<<<NH, 256, 0, stream>>>(u_q, v_q, u_k, v_k, u_v, v_v, WabsT, Wv);
  k_m2<<<dim3(NH, 8), 256, 0, stream>>>(Wv, W_out, M2);
  k_phi<<<dim3(BL / 16, NH, 2), 256, 0, stream>>>(qd, kd, WabsT, omega, rffb,
                                                  phiq, phik, qcodes8);
  k_bhist<<<dim3(BB * 8, NCH), 256, 0, stream>>>(kcodes, chist);
  k_bscan<<<BB * 8, 256, 0, stream>>>(chist);
  k_brank<<<dim3(BB * 8, NCH), 256, 0, stream>>>(kcodes, chist, (unsigned char*)krank8);
  k_cand<<<NQ / 4, 256, 0, stream>>>(qcodes8, kcodes8, krank8, cand, nval);
  k_attn<<<NQ / 4, 256, 0, stream>>>(phiq, phik, cand, nval, vd, ctx);
  k_out<<<BL / 16, 256, 0, stream>>>(ctx, M2, b_out, out);
}

// Round 7
// 583.577 us; speedup vs baseline: 1.1823x; 1.1823x over previous
//
#include <hip/hip_runtime.h>
#include <hip/hip_bf16.h>
#include <math.h>

// ---- config (mirrors reference) ----
#define BB 2
#define LL 2048
#define DM 512
#define DK 64
#define NH 8
#define RK 32
#define RFF 128
#define KMAX 64
#define BL (BB*LL)            // 4096
#define NQ (NH*BB*LL)         // 32768 query-head rows
#define NCH 16                // chunks per (b,g) row for bucket build
#define CHW (LL/NCH)          // 128 keys per chunk

#define RFF_SCALE 0.125f                   /* sqrt(2/128) */
#define INV_SQRT_RFF 0.08838834764831845f  /* 1/sqrt(128) */

typedef unsigned long long u64;

// exact per-byte zero detect: 0x80 bit set iff that byte of x is zero
__device__ __forceinline__ unsigned int zbytes(unsigned int x) {
  return ~(((x & 0x7F7F7F7Fu) + 0x7F7F7F7Fu) | x | 0x7F7F7F7Fu);
}
__device__ __forceinline__ u64 zbytes64(u64 x) {
  return ~(((x & 0x7F7F7F7F7F7F7F7Full) + 0x7F7F7F7F7F7F7F7Full) | x | 0x7F7F7F7F7F7F7F7Full);
}

// ================= K1: down projections, 16 rows/block, fused k-codes ==============
// grid (BL/16, 3), block 256. which: 0=q 1=k 2=v.
__global__ __launch_bounds__(256) void k_down_proj(
    const float* __restrict__ q, const float* __restrict__ k, const float* __restrict__ v,
    const float* __restrict__ Wq, const float* __restrict__ bq,
    const float* __restrict__ Wkv, const float* __restrict__ bkv,
    float* __restrict__ qd, float* __restrict__ kd, float* __restrict__ vd,
    unsigned char* __restrict__ kcodes, u64* __restrict__ kcodes8) {
  int r0 = blockIdx.x * 16;
  int which = blockIdx.y;
  const float* src = (which == 0) ? q : (which == 1) ? k : v;
  const float* W   = (which == 0) ? Wq : Wkv;
  const float* bias= (which == 0) ? bq : bkv;
  float* dst       = (which == 0) ? qd : (which == 1) ? kd : vd;
  int tid = threadIdx.x;
  int d = tid & 63, rg = tid >> 6;

  __shared__ float sin_[16][DM];     // 32KB
  const float4* s4 = (const float4*)(src + (size_t)r0 * DM);
  float4* l4 = (float4*)&sin_[0][0];
  #pragma unroll
  for (int u = 0; u < 8; ++u) l4[tid + u * 256] = s4[tid + u * 256];
  __syncthreads();

  float acc[4] = {0.f, 0.f, 0.f, 0.f};
  for (int t4 = 0; t4 < DM / 4; ++t4) {
    float w[4];
    #pragma unroll
    for (int u = 0; u < 4; ++u) w[u] = W[(t4 * 4 + u) * DK + d];
    #pragma unroll
    for (int r = 0; r < 4; ++r) {
      float4 c4 = *(const float4*)&sin_[rg * 4 + r][t4 * 4];   // wave-broadcast b128
      acc[r] = fmaf(c4.x, w[0], acc[r]);
      acc[r] = fmaf(c4.y, w[1], acc[r]);
      acc[r] = fmaf(c4.z, w[2], acc[r]);
      acc[r] = fmaf(c4.w, w[3], acc[r]);
    }
  }
  float bs = bias[d];
  #pragma unroll
  for (int r = 0; r < 4; ++r) {
    int R = r0 + rg * 4 + r;
    float val = acc[r] + bs;
    dst[(size_t)R * DK + d] = val;
    if (which == 1) {
      u64 m = __ballot(val > 0.f);   // bit d = sign of feature d; byte g = code of group g
      int b = R >> 11, j = R & 2047;
      if (d == 0) kcodes8[((size_t)b << 11) + j] = m;
      if (d < 8)
        kcodes[(((size_t)b * 8 + d) << 11) + j] = (unsigned char)((m >> (8 * d)) & 0xFF);
    }
  }
}

// ===== K2: per-head precompute W_absorb (TRANSPOSED) and Wv = u_v@v_v =====
__global__ __launch_bounds__(256) void k_head_pre(
    const float* __restrict__ u_q, const float* __restrict__ v_q,
    const float* __restrict__ u_k, const float* __restrict__ v_k,
    const float* __restrict__ u_v, const float* __restrict__ v_v,
    float* __restrict__ WabsT, float* __restrict__ Wv) {
  int h = blockIdx.x, tid = threadIdx.x;
  __shared__ float sU[DK * RK];
  __shared__ float sV[RK * DK];
  __shared__ float sWUQ[DK * DK];
  __shared__ float sWUK[DK * DK];
  for (int e = tid; e < DK * RK; e += 256) sU[e] = u_q[h * DK * RK + e];
  for (int e = tid; e < RK * DK; e += 256) sV[e] = v_q[h * RK * DK + e];
  __syncthreads();
  for (int e = tid; e < DK * DK; e += 256) {
    int r = e >> 6, c = e & 63;
    float a = 0.f;
    for (int t = 0; t < RK; ++t) a = fmaf(sU[r * RK + t], sV[t * DK + c], a);
    sWUQ[e] = a;
  }
  __syncthreads();
  for (int e = tid; e < DK * RK; e += 256) sU[e] = u_k[h * DK * RK + e];
  for (int e = tid; e < RK * DK; e += 256) sV[e] = v_k[h * RK * DK + e];
  __syncthreads();
  for (int e = tid; e < DK * DK; e += 256) {
    int r = e >> 6, c = e & 63;
    float a = 0.f;
    for (int t = 0; t < RK; ++t) a = fmaf(sU[r * RK + t], sV[t * DK + c], a);
    sWUK[e] = a;
  }
  __syncthreads();
  for (int e = tid; e < DK * DK; e += 256) {
    int a_ = e >> 6, q_ = e & 63;
    float a = 0.f;
    for (int c = 0; c < DK; ++c) a = fmaf(sWUK[c * DK + a_], sWUQ[c * DK + q_], a);
    WabsT[h * DK * DK + q_ * DK + a_] = a;
  }
  __syncthreads();
  for (int e = tid; e < DK * RK; e += 256) sU[e] = u_v[h * DK * RK + e];
  __syncthreads();
  const float* vv = v_v + (size_t)h * RK * DM;
  for (int e = tid; e < DK * DM; e += 256) {
    int d = e >> 9, o = e & 511;
    float a = 0.f;
    for (int c = 0; c < RK; ++c) a = fmaf(sU[d * RK + c], vv[c * DM + o], a);
    Wv[(size_t)h * DK * DM + e] = a;
  }
}

// ===== K3: M2 = Wv @ W_out (per-head slice), 8 rows/block. grid (NH, 8) =====
__global__ __launch_bounds__(256) void k_m2(
    const float* __restrict__ Wv, const float* __restrict__ W_out, float* __restrict__ M2) {
  int h = blockIdx.x, d0 = blockIdx.y * 8;
  int tid = threadIdx.x;
  __shared__ float4 sWv4[8][DM / 4];
  const float4* g4 = (const float4*)(Wv + ((size_t)h * DK + d0) * DM);
  float4* l4 = &sWv4[0][0];
  #pragma unroll
  for (int u = 0; u < 4; ++u) l4[tid + u * 256] = g4[tid + u * 256];
  __syncthreads();
  float a0[8], a1[8];
  #pragma unroll
  for (int r = 0; r < 8; ++r) { a0[r] = 0.f; a1[r] = 0.f; }
  const float* Wo = W_out + (size_t)h * DM * DM;
  for (int p4 = 0; p4 < DM / 4; ++p4) {
    float m0[4], m1[4];
    #pragma unroll
    for (int u = 0; u < 4; ++u) {
      m0[u] = Wo[(size_t)(p4 * 4 + u) * DM + tid];
      m1[u] = Wo[(size_t)(p4 * 4 + u) * DM + tid + 256];
    }
    #pragma unroll
    for (int r = 0; r < 8; ++r) {
      float4 c4 = sWv4[r][p4];
      a0[r] = fmaf(c4.x, m0[0], a0[r]); a0[r] = fmaf(c4.y, m0[1], a0[r]);
      a0[r] = fmaf(c4.z, m0[2], a0[r]); a0[r] = fmaf(c4.w, m0[3], a0[r]);
      a1[r] = fmaf(c4.x, m1[0], a1[r]); a1[r] = fmaf(c4.y, m1[1], a1[r]);
      a1[r] = fmaf(c4.z, m1[2], a1[r]); a1[r] = fmaf(c4.w, m1[3], a1[r]);
    }
  }
  #pragma unroll
  for (int r = 0; r < 8; ++r) {
    size_t row = (size_t)h * DK + d0 + r;
    M2[row * DM + tid] = a0[r];
    M2[row * DM + tid + 256] = a1[r];
  }
}

// ===== K4: fused phi_q (+q-codes via ballot) / phi_k. grid (BL/16, NH, 2) =====
__global__ __launch_bounds__(256, 4) void k_phi(
    const float* __restrict__ qd, const float* __restrict__ kd,
    const float* __restrict__ WabsT,
    const float* __restrict__ omega, const float* __restrict__ rff_bias,
    float* __restrict__ phiq, float* __restrict__ phik,
    u64* __restrict__ qcodes8) {
  int r0 = blockIdx.x * 16;
  int h = blockIdx.y;
  int isK = blockIdx.z;
  int tid = threadIdx.x;
  __shared__ float sq[16][DK];
  __shared__ float qp[16][DK];

  if (!isK) {
    const float4* g4 = (const float4*)(qd + (size_t)r0 * DK);
    float4* l4 = (float4*)&sq[0][0];
    l4[tid] = g4[tid];
    __syncthreads();
    int a_ = tid & 63, rg = tid >> 6;
    float acc[4] = {0.f, 0.f, 0.f, 0.f};
    const float* Wt = WabsT + h * DK * DK;
    for (int t = 0; t < DK; ++t) {
      float w = Wt[t * DK + a_];
      #pragma unroll
      for (int r = 0; r < 4; ++r) acc[r] = fmaf(sq[rg * 4 + r][t], w, acc[r]);
    }
    #pragma unroll
    for (int r = 0; r < 4; ++r) {
      u64 m = __ballot(acc[r] > 0.f);       // bit a_ = sign of Qp dim a_
      int R = r0 + rg * 4 + r;
      if (a_ == 0) {
        int b = R >> 11, i = R & 2047;
        qcodes8[(((size_t)h * BB + b) << 11) + i] = m;
      }
      qp[R - r0][a_] = acc[r];
    }
    __syncthreads();
  } else {
    const float4* g4 = (const float4*)(kd + (size_t)r0 * DK);
    float4* l4 = (float4*)&qp[0][0];
    l4[tid] = g4[tid];
    __syncthreads();
  }

  int col = tid & 127, rg2 = tid >> 7;
  float acc[8];
  float bias = rff_bias[h * RFF + col];
  #pragma unroll
  for (int r = 0; r < 8; ++r) acc[r] = bias;
  const float* om = omega + (size_t)h * DK * RFF;
  #pragma unroll 4
  for (int d4 = 0; d4 < DK / 4; ++d4) {
    float w[4];
    #pragma unroll
    for (int u = 0; u < 4; ++u) w[u] = om[(size_t)(d4 * 4 + u) * RFF + col];
    #pragma unroll
    for (int r = 0; r < 8; ++r) {
      float4 c4 = *(const float4*)&qp[rg2 * 8 + r][d4 * 4];
      acc[r] = fmaf(c4.x, w[0], acc[r]); acc[r] = fmaf(c4.y, w[1], acc[r]);
      acc[r] = fmaf(c4.z, w[2], acc[r]); acc[r] = fmaf(c4.w, w[3], acc[r]);
    }
  }
  float* dst = isK ? phik : phiq;
  #pragma unroll
  for (int r = 0; r < 8; ++r) {
    int R = r0 + rg2 * 8 + r;
    dst[((size_t)h * BL + R) * RFF + col] = cosf(acc[r]) * RFF_SCALE;
  }
}

// ===== K5a: per-chunk histogram. grid (16 bg, 16 ch), block 256 (thread = code) =====
__global__ __launch_bounds__(256) void k_bhist(
    const unsigned char* __restrict__ kcodes, int* __restrict__ chist) {
  int bg = blockIdx.x, ch = blockIdx.y;
  int c = threadIdx.x;
  __shared__ unsigned int wrd[CHW / 4];
  if (c < CHW / 4)
    wrd[c] = ((const unsigned int*)(kcodes + (size_t)bg * LL + ch * CHW))[c];
  __syncthreads();
  unsigned int pat = (unsigned)c * 0x01010101u;
  int cnt = 0;
  #pragma unroll
  for (int t = 0; t < CHW / 4; ++t)
    cnt += __popc(zbytes(wrd[t] ^ pat));
  chist[((size_t)bg * NCH + ch) * 256 + c] = cnt;
}

// ===== K5b: exclusive scan over chunks (in-place). grid 16, block 256 =====
__global__ __launch_bounds__(256) void k_bscan(int* __restrict__ chist) {
  int bg = blockIdx.x, c = threadIdx.x;
  int base = 0;
  #pragma unroll
  for (int ch = 0; ch < NCH; ++ch) {
    size_t idx = ((size_t)bg * NCH + ch) * 256 + c;
    int v = chist[idx];
    chist[idx] = base;
    base += v;
  }
}

// ===== K5c: per-key in-bucket rank (byte g of krank8[b][j]). grid (16,16) =====
__global__ __launch_bounds__(256) void k_brank(
    const unsigned char* __restrict__ kcodes, const int* __restrict__ chist,
    unsigned char* __restrict__ krankb) {
  int bg = blockIdx.x, ch = blockIdx.y;
  int c = threadIdx.x;
  __shared__ unsigned int wrd[CHW / 4];
  if (c < CHW / 4)
    wrd[c] = ((const unsigned int*)(kcodes + (size_t)bg * LL + ch * CHW))[c];
  __syncthreads();
  int pos = chist[((size_t)bg * NCH + ch) * 256 + c];
  unsigned int pat = (unsigned)c * 0x01010101u;
  int b = bg >> 3, g = bg & 7;
  int j0 = ch * CHW;
  for (int t = 0; t < CHW / 4; ++t) {
    unsigned int zm = zbytes(wrd[t] ^ pat);
    while (zm) {
      int byte = (__ffs(zm) - 1) >> 3;
      int j = j0 + t * 4 + byte;
      krankb[((((size_t)b << 11) + j) << 3) + g] = (unsigned char)(pos > 254 ? 254 : pos);
      ++pos;
      zm &= zm - 1;
    }
  }
}

// ===== K6: FUSED candidates + scores + softmax + weighted V sum =====
// grid NQ/4 (XCD-chunk-swizzled), block 256 = 4 waves, one query per wave.
// Score phase: 4 lanes cooperate per candidate -> each float4-gather instr
// touches 16 distinct 64B L2 granules (vs 64 for lane-per-candidate).
__global__ __launch_bounds__(256) void k_attn(
    const u64* __restrict__ qcodes8, const u64* __restrict__ kcodes8,
    const u64* __restrict__ krank8,
    const float* __restrict__ phiq, const float* __restrict__ phik,
    const float* __restrict__ vd, float* __restrict__ ctx) {
  __shared__ __align__(16) int   lcs[4][KMAX];   // candidate indices
  __shared__ __align__(16) float lw [4][KMAX];   // softmax weights
  __shared__ float  ssc[4][KMAX];                // raw scores
  __shared__ float4 sph[4][RFF / 4];             // phiq row per wave
  // XCD-chunked swizzle: XCD x owns contiguous query range -> its L2 holds
  // one head's phik (2MB) + vd (1MB).
  int swz = (blockIdx.x & 7) * ((NQ / 4) / 8) + (blockIdx.x >> 3);
  int lane = threadIdx.x & 63;
  int wv = threadIdx.x >> 6;
  int qidx = swz * 4 + wv;
  int h = qidx >> 12;
  int b = (qidx >> 11) & 1;
  int i = qidx & 2047;
  int base = qidx - i;                 // (h*BB+b)*LL in phi-row space

  // ---- Phase A: candidate scan (all-wave ballot; ascending order) ----
  lcs[wv][lane] = 0;
  u64 qc = qcodes8[(((size_t)h * BB + b) << 11) + i];   // wave-uniform
  const u64* kc8 = kcodes8 + ((size_t)b << 11);
  const u64* kr8 = krank8 + ((size_t)b << 11);
  int cnt = 0;
  for (int w = 0; w < LL / 64; ++w) {
    int j = w * 64 + lane;
    u64 x = kc8[j] ^ qc;
    u64 zb = zbytes64(x);                         // 0x80 per matching-code byte
    u64 t = kr8[j] & 0xC0C0C0C0C0C0C0C0ull;       // rank>=64 => bit6|bit7 set
    u64 tt = (t | (t << 1)) & 0x8080808080808080ull;
    bool is_cand = (zb & ~tt) != 0ull;
    u64 mask = __ballot(is_cand);
    int pos = cnt + __popcll(mask & ((1ull << lane) - 1ull));
    if (is_cand && pos < KMAX) lcs[wv][pos] = j;
    cnt += __popcll(mask);
    if (cnt >= KMAX) break;                       // wave-uniform
  }
  int nv = cnt < KMAX ? cnt : KMAX;

  // ---- Phase B: stage this query's phiq row (512B) ----
  if (lane < RFF / 4)
    sph[wv][lane] = ((const float4*)(phiq + (size_t)qidx * RFF))[lane];

  // ---- Phase C: scores, 4 lanes per candidate (coalesced 64B per candidate) ----
  int k16 = lane >> 2, f = lane & 3;
  #pragma unroll
  for (int cb = 0; cb < 4; ++cb) {
    int cd = cb * 16 + k16;
    int col = lcs[wv][cd];
    const float4* rp = (const float4*)(phik + (size_t)(base + col) * RFF);
    float p = 0.f;
    #pragma unroll
    for (int t = 0; t < 8; ++t) {
      int idx = t * 4 + f;
      float4 kv = rp[idx];           // lanes 4k..4k+3: one 64B granule of row
      float4 qv = sph[wv][idx];      // 16-way same-address broadcast
      p += kv.x * qv.x + kv.y * qv.y + kv.z * qv.z + kv.w * qv.w;
    }
    p += __shfl_xor(p, 1);
    p += __shfl_xor(p, 2);           // all 4 lanes hold the full dot
    if (f == 0) ssc[wv][cd] = p * INV_SQRT_RFF;
  }

  // ---- Phase D: softmax over the 64 slots (wave-local LDS exchange) ----
  float s = (lane < nv) ? ssc[wv][lane] : -1e30f;
  float m = s;
  #pragma unroll
  for (int off = 32; off >= 1; off >>= 1) m = fmaxf(m, __shfl_xor(m, off));
  float e = expf(s - m);
  float sum = e;
  #pragma unroll
  for (int off = 32; off >= 1; off >>= 1) sum += __shfl_xor(sum, off);
  float w_ = (lane < nv) ? (e / sum) : 0.f;
  lw[wv][lane] = w_;

  // ---- Phase E: weighted V accumulate (lane = d; vb rows coalesced 256B) ----
  float acc = 0.f;
  const float* vb = vd + (size_t)b * LL * DK;
  for (int k4 = 0; k4 < KMAX / 4; ++k4) {
    float4 w4 = *(const float4*)&lw[wv][k4 * 4];   // broadcast
    int4   c4 = *(const int4*)&lcs[wv][k4 * 4];
    acc = fmaf(w4.x, vb[(size_t)c4.x * DK + lane], acc);
    acc = fmaf(w4.y, vb[(size_t)c4.y * DK + lane], acc);
    acc = fmaf(w4.z, vb[(size_t)c4.z * DK + lane], acc);
    acc = fmaf(w4.w, vb[(size_t)c4.w * DK + lane], acc);
  }
  ctx[((size_t)(b * LL + i)) * (NH * DK) + h * DK + lane] = acc;
}

// ===== K8: out = ctx @ M2 + b_out, 16 rows/block. grid BL/16 =====
__global__ __launch_bounds__(256) void k_out(
    const float* __restrict__ ctx, const float* __restrict__ M2,
    const float* __restrict__ b_out, float* __restrict__ out) {
  int r0 = blockIdx.x * 16;
  int tid = threadIdx.x;
  __shared__ float4 sctx4[16][DM / 4];
  const float4* g4 = (const float4*)(ctx + (size_t)r0 * DM);
  float4* l4 = &sctx4[0][0];
  #pragma unroll
  for (int u = 0; u < 8; ++u) l4[tid + u * 256] = g4[tid + u * 256];
  __syncthreads();
  float a0[16], a1[16];
  #pragma unroll
  for (int r = 0; r < 16; ++r) { a0[r] = 0.f; a1[r] = 0.f; }
  for (int p4 = 0; p4 < DM / 4; ++p4) {
    float m0[4], m1[4];
    #pragma unroll
    for (int u = 0; u < 4; ++u) {
      m0[u] = M2[(size_t)(p4 * 4 + u) * DM + tid];
      m1[u] = M2[(size_t)(p4 * 4 + u) * DM + tid + 256];
    }
    #pragma unroll
    for (int r = 0; r < 16; ++r) {
      float4 c4 = sctx4[r][p4];
      a0[r] = fmaf(c4.x, m0[0], a0[r]); a0[r] = fmaf(c4.y, m0[1], a0[r]);
      a0[r] = fmaf(c4.z, m0[2], a0[r]); a0[r] = fmaf(c4.w, m0[3], a0[r]);
      a1[r] = fmaf(c4.x, m1[0], a1[r]); a1[r] = fmaf(c4.y, m1[1], a1[r]);
      a1[r] = fmaf(c4.z, m1[2], a1[r]); a1[r] = fmaf(c4.w, m1[3], a1[r]);
    }
  }
  float b0 = b_out[tid], b1 = b_out[tid + 256];
  #pragma unroll
  for (int r = 0; r < 16; ++r) {
    out[(size_t)(r0 + r) * DM + tid] = a0[r] + b0;
    out[(size_t)(r0 + r) * DM + tid + 256] = a1[r] + b1;
  }
}

extern "C" void kernel_launch(void* const* d_in, const int* in_sizes, int n_in,
                              void* d_out, int out_size, void* d_ws, size_t ws_size,
                              hipStream_t stream) {
  const float* query = (const float*)d_in[0];
  const float* key   = (const float*)d_in[1];
  const float* value = (const float*)d_in[2];
  const float* Wq    = (const float*)d_in[3];
  const float* bq    = (const float*)d_in[4];
  const float* Wkv   = (const float*)d_in[5];
  const float* bkv   = (const float*)d_in[6];
  const float* u_q   = (const float*)d_in[7];
  const float* v_q   = (const float*)d_in[8];
  const float* u_k   = (const float*)d_in[9];
  const float* v_k   = (const float*)d_in[10];
  const float* u_v   = (const float*)d_in[11];
  const float* v_v   = (const float*)d_in[12];
  const float* omega = (const float*)d_in[13];
  const float* rffb  = (const float*)d_in[14];
  const float* W_out = (const float*)d_in[15];
  const float* b_out = (const float*)d_in[16];
  float* out = (float*)d_out;

  // ---- workspace carve (256B aligned) ----
  size_t off = 0;
  char* ws = (char*)d_ws;
  auto carve = [&](size_t bytes) -> void* {
    void* p = ws + off;
    off += (bytes + 255) & ~(size_t)255;
    return p;
  };
  float* qd    = (float*)carve((size_t)BL * DK * 4);
  float* kd    = (float*)carve((size_t)BL * DK * 4);
  float* vd    = (float*)carve((size_t)BL * DK * 4);
  float* WabsT = (float*)carve((size_t)NH * DK * DK * 4);
  float* Wv    = (float*)carve((size_t)NH * DK * DM * 4);
  float* M2    = (float*)carve((size_t)NH * DK * DM * 4);
  float* phiq  = (float*)carve((size_t)NQ * RFF * 4);
  float* phik  = (float*)carve((size_t)NQ * RFF * 4);
  unsigned char* kcodes = (unsigned char*)carve((size_t)BB * 8 * LL);
  u64* kcodes8 = (u64*)carve((size_t)BB * LL * 8);
  u64* qcodes8 = (u64*)carve((size_t)NH * BB * LL * 8);
  u64* krank8  = (u64*)carve((size_t)BB * LL * 8);
  int* chist = (int*)carve((size_t)BB * 8 * NCH * 256 * 4);
  float* ctx = (float*)carve((size_t)BL * NH * DK * 4);
  (void)ws_size;

  // ---- launches (fixed sequence, all on stream) ----
  k_down_proj<<<dim3(BL / 16, 3), 256, 0, stream>>>(query, key, value, Wq, bq, Wkv, bkv,
                                                    qd, kd, vd, kcodes, kcodes8);
  k_head_pre<<<NH, 256, 0, stream>>>(u_q, v_q, u_k, v_k, u_v, v_v, WabsT, Wv);
  k_m2<<<dim3(NH, 8), 256, 0, stream>>>(Wv, W_out, M2);
  k_phi<<<dim3(BL / 16, NH, 2), 256, 0, stream>>>(qd, kd, WabsT, omega, rffb,
                                                  phiq, phik, qcodes8);
  k_bhist<<<dim3(BB * 8, NCH), 256, 0, stream>>>(kcodes, chist);
  k_bscan<<<BB * 8, 256, 0, stream>>>(chist);
  k_brank<<<dim3(BB * 8, NCH), 256, 0, stream>>>(kcodes, chist, (unsigned char*)krank8);
  k_attn<<<NQ / 4, 256, 0, stream>>>(qcodes8, kcodes8, krank8, phiq, phik, vd, ctx);
  k_out<<<BL / 16, 256, 0, stream>>>(ctx, M2, b_out, out);
}

// Round 8
// 522.941 us; speedup vs baseline: 1.3194x; 1.1160x over previous
//
#include <hip/hip_runtime.h>
#include <hip/hip_bf16.h>
#include <math.h>

// ---- config (mirrors reference) ----
#define BB 2
#define LL 2048
#define DM 512
#define DK 64
#define NH 8
#define RK 32
#define RFF 128
#define KMAX 64
#define BL (BB*LL)            // 4096
#define NQ (NH*BB*LL)         // 32768 query-head rows
#define NCH 16                // chunks per (b,g) row for bucket build
#define CHW (LL/NCH)          // 128 keys per chunk

#define RFF_SCALE 0.125f                   /* sqrt(2/128) */
#define INV_SQRT_RFF 0.08838834764831845f  /* 1/sqrt(128) */

typedef unsigned long long u64;

// exact per-byte zero detect: 0x80 bit set iff that byte of x is zero
__device__ __forceinline__ unsigned int zbytes(unsigned int x) {
  return ~(((x & 0x7F7F7F7Fu) + 0x7F7F7F7Fu) | x | 0x7F7F7F7Fu);
}

// ================= K1: down projections, 16 rows/block, fused k-codes ==============
// grid (BL/16, 3), block 256. which: 0=q 1=k 2=v.
__global__ __launch_bounds__(256) void k_down_proj(
    const float* __restrict__ q, const float* __restrict__ k, const float* __restrict__ v,
    const float* __restrict__ Wq, const float* __restrict__ bq,
    const float* __restrict__ Wkv, const float* __restrict__ bkv,
    float* __restrict__ qd, float* __restrict__ kd, float* __restrict__ vd,
    unsigned char* __restrict__ kcodes) {
  int r0 = blockIdx.x * 16;
  int which = blockIdx.y;
  const float* src = (which == 0) ? q : (which == 1) ? k : v;
  const float* W   = (which == 0) ? Wq : Wkv;
  const float* bias= (which == 0) ? bq : bkv;
  float* dst       = (which == 0) ? qd : (which == 1) ? kd : vd;
  int tid = threadIdx.x;
  int d = tid & 63, rg = tid >> 6;

  __shared__ float sin_[16][DM];     // 32KB
  const float4* s4 = (const float4*)(src + (size_t)r0 * DM);
  float4* l4 = (float4*)&sin_[0][0];
  #pragma unroll
  for (int u = 0; u < 8; ++u) l4[tid + u * 256] = s4[tid + u * 256];
  __syncthreads();

  float acc[4] = {0.f, 0.f, 0.f, 0.f};
  for (int t4 = 0; t4 < DM / 4; ++t4) {
    float w[4];
    #pragma unroll
    for (int u = 0; u < 4; ++u) w[u] = W[(t4 * 4 + u) * DK + d];
    #pragma unroll
    for (int r = 0; r < 4; ++r) {
      float4 c4 = *(const float4*)&sin_[rg * 4 + r][t4 * 4];   // wave-broadcast b128
      acc[r] = fmaf(c4.x, w[0], acc[r]);
      acc[r] = fmaf(c4.y, w[1], acc[r]);
      acc[r] = fmaf(c4.z, w[2], acc[r]);
      acc[r] = fmaf(c4.w, w[3], acc[r]);
    }
  }
  float bs = bias[d];
  #pragma unroll
  for (int r = 0; r < 4; ++r) {
    int R = r0 + rg * 4 + r;
    float val = acc[r] + bs;
    dst[(size_t)R * DK + d] = val;
    if (which == 1) {
      u64 m = __ballot(val > 0.f);   // bit d = sign of feature d; byte g = code of group g
      if (d < 8) {
        int b = R >> 11, j = R & 2047;
        kcodes[(((size_t)b * 8 + d) << 11) + j] = (unsigned char)((m >> (8 * d)) & 0xFF);
      }
    }
  }
}

// ===== K2: per-head precompute W_absorb (TRANSPOSED) and Wv = u_v@v_v =====
__global__ __launch_bounds__(256) void k_head_pre(
    const float* __restrict__ u_q, const float* __restrict__ v_q,
    const float* __restrict__ u_k, const float* __restrict__ v_k,
    const float* __restrict__ u_v, const float* __restrict__ v_v,
    float* __restrict__ WabsT, float* __restrict__ Wv) {
  int h = blockIdx.x, tid = threadIdx.x;
  __shared__ float sU[DK * RK];
  __shared__ float sV[RK * DK];
  __shared__ float sWUQ[DK * DK];
  __shared__ float sWUK[DK * DK];
  for (int e = tid; e < DK * RK; e += 256) sU[e] = u_q[h * DK * RK + e];
  for (int e = tid; e < RK * DK; e += 256) sV[e] = v_q[h * RK * DK + e];
  __syncthreads();
  for (int e = tid; e < DK * DK; e += 256) {
    int r = e >> 6, c = e & 63;
    float a = 0.f;
    for (int t = 0; t < RK; ++t) a = fmaf(sU[r * RK + t], sV[t * DK + c], a);
    sWUQ[e] = a;
  }
  __syncthreads();
  for (int e = tid; e < DK * RK; e += 256) sU[e] = u_k[h * DK * RK + e];
  for (int e = tid; e < RK * DK; e += 256) sV[e] = v_k[h * RK * DK + e];
  __syncthreads();
  for (int e = tid; e < DK * DK; e += 256) {
    int r = e >> 6, c = e & 63;
    float a = 0.f;
    for (int t = 0; t < RK; ++t) a = fmaf(sU[r * RK + t], sV[t * DK + c], a);
    sWUK[e] = a;
  }
  __syncthreads();
  for (int e = tid; e < DK * DK; e += 256) {
    int a_ = e >> 6, q_ = e & 63;
    float a = 0.f;
    for (int c = 0; c < DK; ++c) a = fmaf(sWUK[c * DK + a_], sWUQ[c * DK + q_], a);
    WabsT[h * DK * DK + q_ * DK + a_] = a;
  }
  __syncthreads();
  for (int e = tid; e < DK * RK; e += 256) sU[e] = u_v[h * DK * RK + e];
  __syncthreads();
  const float* vv = v_v + (size_t)h * RK * DM;
  for (int e = tid; e < DK * DM; e += 256) {
    int d = e >> 9, o = e & 511;
    float a = 0.f;
    for (int c = 0; c < RK; ++c) a = fmaf(sU[d * RK + c], vv[c * DM + o], a);
    Wv[(size_t)h * DK * DM + e] = a;
  }
}

// ===== K3: M2 = Wv @ W_out (per-head slice), 8 rows/block. grid (NH, 8) =====
__global__ __launch_bounds__(256) void k_m2(
    const float* __restrict__ Wv, const float* __restrict__ W_out, float* __restrict__ M2) {
  int h = blockIdx.x, d0 = blockIdx.y * 8;
  int tid = threadIdx.x;
  __shared__ float4 sWv4[8][DM / 4];
  const float4* g4 = (const float4*)(Wv + ((size_t)h * DK + d0) * DM);
  float4* l4 = &sWv4[0][0];
  #pragma unroll
  for (int u = 0; u < 4; ++u) l4[tid + u * 256] = g4[tid + u * 256];
  __syncthreads();
  float a0[8], a1[8];
  #pragma unroll
  for (int r = 0; r < 8; ++r) { a0[r] = 0.f; a1[r] = 0.f; }
  const float* Wo = W_out + (size_t)h * DM * DM;
  for (int p4 = 0; p4 < DM / 4; ++p4) {
    float m0[4], m1[4];
    #pragma unroll
    for (int u = 0; u < 4; ++u) {
      m0[u] = Wo[(size_t)(p4 * 4 + u) * DM + tid];
      m1[u] = Wo[(size_t)(p4 * 4 + u) * DM + tid + 256];
    }
    #pragma unroll
    for (int r = 0; r < 8; ++r) {
      float4 c4 = sWv4[r][p4];
      a0[r] = fmaf(c4.x, m0[0], a0[r]); a0[r] = fmaf(c4.y, m0[1], a0[r]);
      a0[r] = fmaf(c4.z, m0[2], a0[r]); a0[r] = fmaf(c4.w, m0[3], a0[r]);
      a1[r] = fmaf(c4.x, m1[0], a1[r]); a1[r] = fmaf(c4.y, m1[1], a1[r]);
      a1[r] = fmaf(c4.z, m1[2], a1[r]); a1[r] = fmaf(c4.w, m1[3], a1[r]);
    }
  }
  #pragma unroll
  for (int r = 0; r < 8; ++r) {
    size_t row = (size_t)h * DK + d0 + r;
    M2[row * DM + tid] = a0[r];
    M2[row * DM + tid + 256] = a1[r];
  }
}

// ===== K4: fused phi_q (+q-codes via ballot) / phi_k. grid (BL/16, NH, 2) =====
__global__ __launch_bounds__(256, 4) void k_phi(
    const float* __restrict__ qd, const float* __restrict__ kd,
    const float* __restrict__ WabsT,
    const float* __restrict__ omega, const float* __restrict__ rff_bias,
    float* __restrict__ phiq, float* __restrict__ phik,
    u64* __restrict__ qcodes8) {
  int r0 = blockIdx.x * 16;
  int h = blockIdx.y;
  int isK = blockIdx.z;
  int tid = threadIdx.x;
  __shared__ float sq[16][DK];
  __shared__ float qp[16][DK];

  if (!isK) {
    const float4* g4 = (const float4*)(qd + (size_t)r0 * DK);
    float4* l4 = (float4*)&sq[0][0];
    l4[tid] = g4[tid];
    __syncthreads();
    int a_ = tid & 63, rg = tid >> 6;
    float acc[4] = {0.f, 0.f, 0.f, 0.f};
    const float* Wt = WabsT + h * DK * DK;
    for (int t = 0; t < DK; ++t) {
      float w = Wt[t * DK + a_];
      #pragma unroll
      for (int r = 0; r < 4; ++r) acc[r] = fmaf(sq[rg * 4 + r][t], w, acc[r]);
    }
    #pragma unroll
    for (int r = 0; r < 4; ++r) {
      u64 m = __ballot(acc[r] > 0.f);       // bit a_ = sign of Qp dim a_
      int R = r0 + rg * 4 + r;
      if (a_ == 0) {
        int b = R >> 11, i = R & 2047;
        qcodes8[(((size_t)h * BB + b) << 11) + i] = m;
      }
      qp[R - r0][a_] = acc[r];
    }
    __syncthreads();
  } else {
    const float4* g4 = (const float4*)(kd + (size_t)r0 * DK);
    float4* l4 = (float4*)&qp[0][0];
    l4[tid] = g4[tid];
    __syncthreads();
  }

  int col = tid & 127, rg2 = tid >> 7;
  float acc[8];
  float bias = rff_bias[h * RFF + col];
  #pragma unroll
  for (int r = 0; r < 8; ++r) acc[r] = bias;
  const float* om = omega + (size_t)h * DK * RFF;
  #pragma unroll 4
  for (int d4 = 0; d4 < DK / 4; ++d4) {
    float w[4];
    #pragma unroll
    for (int u = 0; u < 4; ++u) w[u] = om[(size_t)(d4 * 4 + u) * RFF + col];
    #pragma unroll
    for (int r = 0; r < 8; ++r) {
      float4 c4 = *(const float4*)&qp[rg2 * 8 + r][d4 * 4];
      acc[r] = fmaf(c4.x, w[0], acc[r]); acc[r] = fmaf(c4.y, w[1], acc[r]);
      acc[r] = fmaf(c4.z, w[2], acc[r]); acc[r] = fmaf(c4.w, w[3], acc[r]);
    }
  }
  float* dst = isK ? phik : phiq;
  #pragma unroll
  for (int r = 0; r < 8; ++r) {
    int R = r0 + rg2 * 8 + r;
    dst[((size_t)h * BL + R) * RFF + col] = cosf(acc[r]) * RFF_SCALE;
  }
}

// ===== K5a: per-chunk histogram. grid (16 bg, 16 ch), block 256 (thread = code) =====
__global__ __launch_bounds__(256) void k_bhist(
    const unsigned char* __restrict__ kcodes, int* __restrict__ chist) {
  int bg = blockIdx.x, ch = blockIdx.y;
  int c = threadIdx.x;
  __shared__ unsigned int wrd[CHW / 4];
  if (c < CHW / 4)
    wrd[c] = ((const unsigned int*)(kcodes + (size_t)bg * LL + ch * CHW))[c];
  __syncthreads();
  unsigned int pat = (unsigned)c * 0x01010101u;
  int cnt = 0;
  #pragma unroll
  for (int t = 0; t < CHW / 4; ++t)
    cnt += __popc(zbytes(wrd[t] ^ pat));
  chist[((size_t)bg * NCH + ch) * 256 + c] = cnt;
}

// ===== K5b: exclusive scan over chunks (in-place) + clamped bcnt. grid 16 =====
__global__ __launch_bounds__(256) void k_bscan(
    int* __restrict__ chist, int* __restrict__ bcnt) {
  int bg = blockIdx.x, c = threadIdx.x;
  int base = 0;
  #pragma unroll
  for (int ch = 0; ch < NCH; ++ch) {
    size_t idx = ((size_t)bg * NCH + ch) * 256 + c;
    int v = chist[idx];
    chist[idx] = base;
    base += v;
  }
  bcnt[bg * 256 + c] = base < KMAX ? base : KMAX;
}

// ===== K5c: ordered scatter of first-KMAX indices. grid (16,16), block 256 =====
__global__ __launch_bounds__(256) void k_bscatter(
    const unsigned char* __restrict__ kcodes, const int* __restrict__ chist,
    int* __restrict__ bidx) {
  int bg = blockIdx.x, ch = blockIdx.y;
  int c = threadIdx.x;
  __shared__ unsigned int wrd[CHW / 4];
  if (c < CHW / 4)
    wrd[c] = ((const unsigned int*)(kcodes + (size_t)bg * LL + ch * CHW))[c];
  __syncthreads();
  int pos = chist[((size_t)bg * NCH + ch) * 256 + c];
  if (pos >= KMAX) return;
  unsigned int pat = (unsigned)c * 0x01010101u;
  int* out = bidx + ((size_t)bg * 256 + c) * KMAX;
  int j0 = ch * CHW;
  for (int t = 0; t < CHW / 4; ++t) {
    unsigned int zm = zbytes(wrd[t] ^ pat);
    while (zm) {
      int byte = (__ffs(zm) - 1) >> 3;       // lowest matching byte -> ascending j
      out[pos++] = j0 + t * 4 + byte;
      if (pos >= KMAX) return;
      zm &= zm - 1;
    }
  }
}

// ===== K6: FUSED candidates (bucket-list bitmap union) + scores + softmax + PV =====
// grid NQ/4 (XCD-chunk-swizzled), block 256 = 4 waves, one query per wave.
__global__ __launch_bounds__(256) void k_attn(
    const u64* __restrict__ qcodes8, const int* __restrict__ bcnt,
    const int* __restrict__ bidx,
    const float* __restrict__ phiq, const float* __restrict__ phik,
    const float* __restrict__ vd, float* __restrict__ ctx) {
  __shared__ __align__(16) int   lcs[4][KMAX];   // candidate indices
  __shared__ __align__(16) float lw [4][KMAX];   // softmax weights
  __shared__ float        ssc[4][KMAX];          // raw scores
  __shared__ float4       sph[4][RFF / 4];       // phiq row per wave
  __shared__ unsigned int bm [4][64];            // 2048-bit bitmap, lane = word
  // XCD-chunked swizzle: XCD x owns contiguous query range -> its L2 holds
  // one head's phik (2MB) + vd (1MB).
  int swz = (blockIdx.x & 7) * ((NQ / 4) / 8) + (blockIdx.x >> 3);
  int lane = threadIdx.x & 63;
  int wv = threadIdx.x >> 6;
  int qidx = swz * 4 + wv;
  int h = qidx >> 12;
  int b = (qidx >> 11) & 1;
  int i = qidx & 2047;
  int base = qidx - i;                 // (h*BB+b)*LL in phi-row space

  // ---- Phase A: union of 8 bucket lists via LDS bitmap (wave-local) ----
  lcs[wv][lane] = 0;
  bm[wv][lane] = 0u;
  u64 qc = qcodes8[(((size_t)h * BB + b) << 11) + i];   // wave-uniform
  #pragma unroll
  for (int g = 0; g < 8; ++g) {
    int code = (int)((qc >> (8 * g)) & 255);
    int bk = ((b * 8 + g) << 8) + code;
    int cnt = bcnt[bk];
    if (lane < cnt) {
      int j = bidx[(size_t)bk * KMAX + lane];
      atomicOr(&bm[wv][j >> 5], 1u << (j & 31));
    }
  }
  unsigned int wbits = bm[wv][lane];    // after all ds_or of this wave (program order)
  int cw = __popc(wbits);
  int pre = cw;                          // inclusive prefix sum over lanes
  #pragma unroll
  for (int off = 1; off < 64; off <<= 1) {
    int t = __shfl_up(pre, off);
    if (lane >= off) pre += t;
  }
  int total = __shfl(pre, 63);
  int nv = total < KMAX ? total : KMAX;
  int pos = pre - cw;                    // exclusive base for this word
  while (wbits && pos < KMAX) {
    int bit = __ffs(wbits) - 1;
    wbits &= wbits - 1;
    lcs[wv][pos++] = (lane << 5) + bit;  // ascending global order, cut at 64
  }

  // ---- Phase B: stage this query's phiq row (512B) ----
  if (lane < RFF / 4)
    sph[wv][lane] = ((const float4*)(phiq + (size_t)qidx * RFF))[lane];

  // ---- Phase C: scores, 4 lanes per candidate (coalesced 64B per candidate) ----
  int k16 = lane >> 2, f = lane & 3;
  #pragma unroll
  for (int cb = 0; cb < 4; ++cb) {
    int cd = cb * 16 + k16;
    int col = lcs[wv][cd];
    const float4* rp = (const float4*)(phik + (size_t)(base + col) * RFF);
    float p = 0.f;
    #pragma unroll
    for (int t = 0; t < 8; ++t) {
      int idx = t * 4 + f;
      float4 kv = rp[idx];           // lanes 4k..4k+3: one 64B granule of row
      float4 qv = sph[wv][idx];      // 16-way same-address broadcast
      p += kv.x * qv.x + kv.y * qv.y + kv.z * qv.z + kv.w * qv.w;
    }
    p += __shfl_xor(p, 1);
    p += __shfl_xor(p, 2);           // all 4 lanes hold the full dot
    if (f == 0) ssc[wv][cd] = p * INV_SQRT_RFF;
  }

  // ---- Phase D: softmax over the 64 slots (wave-local LDS exchange) ----
  float s = (lane < nv) ? ssc[wv][lane] : -1e30f;
  float m = s;
  #pragma unroll
  for (int off = 32; off >= 1; off >>= 1) m = fmaxf(m, __shfl_xor(m, off));
  float e = expf(s - m);
  float sum = e;
  #pragma unroll
  for (int off = 32; off >= 1; off >>= 1) sum += __shfl_xor(sum, off);
  float w_ = (lane < nv) ? (e / sum) : 0.f;
  lw[wv][lane] = w_;

  // ---- Phase E: weighted V accumulate (lane = d; vb rows coalesced 256B) ----
  float acc = 0.f;
  const float* vb = vd + (size_t)b * LL * DK;
  for (int k4 = 0; k4 < KMAX / 4; ++k4) {
    float4 w4 = *(const float4*)&lw[wv][k4 * 4];   // broadcast
    int4   c4 = *(const int4*)&lcs[wv][k4 * 4];
    acc = fmaf(w4.x, vb[(size_t)c4.x * DK + lane], acc);
    acc = fmaf(w4.y, vb[(size_t)c4.y * DK + lane], acc);
    acc = fmaf(w4.z, vb[(size_t)c4.z * DK + lane], acc);
    acc = fmaf(w4.w, vb[(size_t)c4.w * DK + lane], acc);
  }
  ctx[((size_t)(b * LL + i)) * (NH * DK) + h * DK + lane] = acc;
}

// ===== K8: out = ctx @ M2 + b_out, 16 rows/block. grid BL/16 =====
__global__ __launch_bounds__(256) void k_out(
    const float* __restrict__ ctx, const float* __restrict__ M2,
    const float* __restrict__ b_out, float* __restrict__ out) {
  int r0 = blockIdx.x * 16;
  int tid = threadIdx.x;
  __shared__ float4 sctx4[16][DM / 4];
  const float4* g4 = (const float4*)(ctx + (size_t)r0 * DM);
  float4* l4 = &sctx4[0][0];
  #pragma unroll
  for (int u = 0; u < 8; ++u) l4[tid + u * 256] = g4[tid + u * 256];
  __syncthreads();
  float a0[16], a1[16];
  #pragma unroll
  for (int r = 0; r < 16; ++r) { a0[r] = 0.f; a1[r] = 0.f; }
  for (int p4 = 0; p4 < DM / 4; ++p4) {
    float m0[4], m1[4];
    #pragma unroll
    for (int u = 0; u < 4; ++u) {
      m0[u] = M2[(size_t)(p4 * 4 + u) * DM + tid];
      m1[u] = M2[(size_t)(p4 * 4 + u) * DM + tid + 256];
    }
    #pragma unroll
    for (int r = 0; r < 16; ++r) {
      float4 c4 = sctx4[r][p4];
      a0[r] = fmaf(c4.x, m0[0], a0[r]); a0[r] = fmaf(c4.y, m0[1], a0[r]);
      a0[r] = fmaf(c4.z, m0[2], a0[r]); a0[r] = fmaf(c4.w, m0[3], a0[r]);
      a1[r] = fmaf(c4.x, m1[0], a1[r]); a1[r] = fmaf(c4.y, m1[1], a1[r]);
      a1[r] = fmaf(c4.z, m1[2], a1[r]); a1[r] = fmaf(c4.w, m1[3], a1[r]);
    }
  }
  float b0 = b_out[tid], b1 = b_out[tid + 256];
  #pragma unroll
  for (int r = 0; r < 16; ++r) {
    out[(size_t)(r0 + r) * DM + tid] = a0[r] + b0;
    out[(size_t)(r0 + r) * DM + tid + 256] = a1[r] + b1;
  }
}

extern "C" void kernel_launch(void* const* d_in, const int* in_sizes, int n_in,
                              void* d_out, int out_size, void* d_ws, size_t ws_size,
                              hipStream_t stream) {
  const float* query = (const float*)d_in[0];
  const float* key   = (const float*)d_in[1];
  const float* value = (const float*)d_in[2];
  const float* Wq    = (const float*)d_in[3];
  const float* bq    = (const float*)d_in[4];
  const float* Wkv   = (const float*)d_in[5];
  const float* bkv   = (const float*)d_in[6];
  const float* u_q   = (const float*)d_in[7];
  const float* v_q   = (const float*)d_in[8];
  const float* u_k   = (const float*)d_in[9];
  const float* v_k   = (const float*)d_in[10];
  const float* u_v   = (const float*)d_in[11];
  const float* v_v   = (const float*)d_in[12];
  const float* omega = (const float*)d_in[13];
  const float* rffb  = (const float*)d_in[14];
  const float* W_out = (const float*)d_in[15];
  const float* b_out = (const float*)d_in[16];
  float* out = (float*)d_out;

  // ---- workspace carve (256B aligned) ----
  size_t off = 0;
  char* ws = (char*)d_ws;
  auto carve = [&](size_t bytes) -> void* {
    void* p = ws + off;
    off += (bytes + 255) & ~(size_t)255;
    return p;
  };
  float* qd    = (float*)carve((size_t)BL * DK * 4);
  float* kd    = (float*)carve((size_t)BL * DK * 4);
  float* vd    = (float*)carve((size_t)BL * DK * 4);
  float* WabsT = (float*)carve((size_t)NH * DK * DK * 4);
  float* Wv    = (float*)carve((size_t)NH * DK * DM * 4);
  float* M2    = (float*)carve((size_t)NH * DK * DM * 4);
  float* phiq  = (float*)carve((size_t)NQ * RFF * 4);
  float* phik  = (float*)carve((size_t)NQ * RFF * 4);
  unsigned char* kcodes = (unsigned char*)carve((size_t)BB * 8 * LL);
  u64* qcodes8 = (u64*)carve((size_t)NH * BB * LL * 8);
  int* chist = (int*)carve((size_t)BB * 8 * NCH * 256 * 4);
  int* bcnt  = (int*)carve((size_t)BB * 8 * 256 * 4);
  int* bidx  = (int*)carve((size_t)BB * 8 * 256 * KMAX * 4);
  float* ctx = (float*)carve((size_t)BL * NH * DK * 4);
  (void)ws_size;

  // ---- launches (fixed sequence, all on stream) ----
  k_down_proj<<<dim3(BL / 16, 3), 256, 0, stream>>>(query, key, value, Wq, bq, Wkv, bkv,
                                                    qd, kd, vd, kcodes);
  k_head_pre<<<NH, 256, 0, stream>>>(u_q, v_q, u_k, v_k, u_v, v_v, WabsT, Wv);
  k_m2<<<dim3(NH, 8), 256, 0, stream>>>(Wv, W_out, M2);
  k_phi<<<dim3(BL / 16, NH, 2), 256, 0, stream>>>(qd, kd, WabsT, omega, rffb,
                                                  phiq, phik, qcodes8);
  k_bhist<<<dim3(BB * 8, NCH), 256, 0, stream>>>(kcodes, chist);
  k_bscan<<<BB * 8, 256, 0, stream>>>(chist, bcnt);
  k_bscatter<<<dim3(BB * 8, NCH), 256, 0, stream>>>(kcodes, chist, bidx);
  k_attn<<<NQ / 4, 256, 0, stream>>>(qcodes8, bcnt, bidx, phiq, phik, vd, ctx);
  k_out<<<BL / 16, 256, 0, stream>>>(ctx, M2, b_out, out);
}

// Round 12
// 430.659 us; speedup vs baseline: 1.6021x; 1.2143x over previous
//
#include <hip/hip_runtime.h>
#include <hip/hip_bf16.h>
#include <math.h>

// ---- config (mirrors reference) ----
#define BB 2
#define LL 2048
#define DM 512
#define DK 64
#define NH 8
#define RK 32
#define RFF 128
#define KMAX 64
#define BL (BB*LL)            // 4096
#define NQ (NH*BB*LL)         // 32768 query-head rows
#define NCH 16                // chunks per (b,g) row for bucket build
#define CHW (LL/NCH)          // 128 keys per chunk

#define RFF_SCALE 0.125f                   /* sqrt(2/128) */
#define INV_SQRT_RFF 0.08838834764831845f  /* 1/sqrt(128) */

typedef unsigned long long u64;

// exact per-byte zero detect: 0x80 bit set iff that byte of x is zero
__device__ __forceinline__ unsigned int zbytes(unsigned int x) {
  return ~(((x & 0x7F7F7F7Fu) + 0x7F7F7F7Fu) | x | 0x7F7F7F7Fu);
}

// ================= K1: down projections, 16 rows/block, fused k-codes ==============
// grid (BL/16, 3), block 256. which: 0=q 1=k 2=v.
__global__ __launch_bounds__(256) void k_down_proj(
    const float* __restrict__ q, const float* __restrict__ k, const float* __restrict__ v,
    const float* __restrict__ Wq, const float* __restrict__ bq,
    const float* __restrict__ Wkv, const float* __restrict__ bkv,
    float* __restrict__ qd, float* __restrict__ kd, float* __restrict__ vd,
    unsigned char* __restrict__ kcodes) {
  int r0 = blockIdx.x * 16;
  int which = blockIdx.y;
  const float* src = (which == 0) ? q : (which == 1) ? k : v;
  const float* W   = (which == 0) ? Wq : Wkv;
  const float* bias= (which == 0) ? bq : bkv;
  float* dst       = (which == 0) ? qd : (which == 1) ? kd : vd;
  int tid = threadIdx.x;
  int d = tid & 63, rg = tid >> 6;

  __shared__ float sin_[16][DM];     // 32KB
  const float4* s4 = (const float4*)(src + (size_t)r0 * DM);
  float4* l4 = (float4*)&sin_[0][0];
  #pragma unroll
  for (int u = 0; u < 8; ++u) l4[tid + u * 256] = s4[tid + u * 256];
  __syncthreads();

  float acc[4] = {0.f, 0.f, 0.f, 0.f};
  for (int t4 = 0; t4 < DM / 4; ++t4) {
    float w[4];
    #pragma unroll
    for (int u = 0; u < 4; ++u) w[u] = W[(t4 * 4 + u) * DK + d];
    #pragma unroll
    for (int r = 0; r < 4; ++r) {
      float4 c4 = *(const float4*)&sin_[rg * 4 + r][t4 * 4];   // wave-broadcast b128
      acc[r] = fmaf(c4.x, w[0], acc[r]);
      acc[r] = fmaf(c4.y, w[1], acc[r]);
      acc[r] = fmaf(c4.z, w[2], acc[r]);
      acc[r] = fmaf(c4.w, w[3], acc[r]);
    }
  }
  float bs = bias[d];
  #pragma unroll
  for (int r = 0; r < 4; ++r) {
    int R = r0 + rg * 4 + r;
    float val = acc[r] + bs;
    dst[(size_t)R * DK + d] = val;
    if (which == 1) {
      u64 m = __ballot(val > 0.f);   // bit d = sign of feature d; byte g = code of group g
      if (d < 8) {
        int b = R >> 11, j = R & 2047;
        kcodes[(((size_t)b * 8 + d) << 11) + j] = (unsigned char)((m >> (8 * d)) & 0xFF);
      }
    }
  }
}

// ===== K2: per-head precompute W_absorb (TRANSPOSED) and Wv = u_v@v_v =====
__global__ __launch_bounds__(256) void k_head_pre(
    const float* __restrict__ u_q, const float* __restrict__ v_q,
    const float* __restrict__ u_k, const float* __restrict__ v_k,
    const float* __restrict__ u_v, const float* __restrict__ v_v,
    float* __restrict__ WabsT, float* __restrict__ Wv) {
  int h = blockIdx.x, tid = threadIdx.x;
  __shared__ float sU[DK * RK];
  __shared__ float sV[RK * DK];
  __shared__ float sWUQ[DK * DK];
  __shared__ float sWUK[DK * DK];
  for (int e = tid; e < DK * RK; e += 256) sU[e] = u_q[h * DK * RK + e];
  for (int e = tid; e < RK * DK; e += 256) sV[e] = v_q[h * RK * DK + e];
  __syncthreads();
  for (int e = tid; e < DK * DK; e += 256) {
    int r = e >> 6, c = e & 63;
    float a = 0.f;
    for (int t = 0; t < RK; ++t) a = fmaf(sU[r * RK + t], sV[t * DK + c], a);
    sWUQ[e] = a;
  }
  __syncthreads();
  for (int e = tid; e < DK * RK; e += 256) sU[e] = u_k[h * DK * RK + e];
  for (int e = tid; e < RK * DK; e += 256) sV[e] = v_k[h * RK * DK + e];
  __syncthreads();
  for (int e = tid; e < DK * DK; e += 256) {
    int r = e >> 6, c = e & 63;
    float a = 0.f;
    for (int t = 0; t < RK; ++t) a = fmaf(sU[r * RK + t], sV[t * DK + c], a);
    sWUK[e] = a;
  }
  __syncthreads();
  for (int e = tid; e < DK * DK; e += 256) {
    int a_ = e >> 6, q_ = e & 63;
    float a = 0.f;
    for (int c = 0; c < DK; ++c) a = fmaf(sWUK[c * DK + a_], sWUQ[c * DK + q_], a);
    WabsT[h * DK * DK + q_ * DK + a_] = a;
  }
  __syncthreads();
  for (int e = tid; e < DK * RK; e += 256) sU[e] = u_v[h * DK * RK + e];
  __syncthreads();
  const float* vv = v_v + (size_t)h * RK * DM;
  for (int e = tid; e < DK * DM; e += 256) {
    int d = e >> 9, o = e & 511;
    float a = 0.f;
    for (int c = 0; c < RK; ++c) a = fmaf(sU[d * RK + c], vv[c * DM + o], a);
    Wv[(size_t)h * DK * DM + e] = a;
  }
}

// ===== K3: M2 = Wv @ W_out (per-head slice), 8 rows/block. grid (NH, 8) =====
__global__ __launch_bounds__(256) void k_m2(
    const float* __restrict__ Wv, const float* __restrict__ W_out, float* __restrict__ M2) {
  int h = blockIdx.x, d0 = blockIdx.y * 8;
  int tid = threadIdx.x;
  __shared__ float4 sWv4[8][DM / 4];
  const float4* g4 = (const float4*)(Wv + ((size_t)h * DK + d0) * DM);
  float4* l4 = &sWv4[0][0];
  #pragma unroll
  for (int u = 0; u < 4; ++u) l4[tid + u * 256] = g4[tid + u * 256];
  __syncthreads();
  float a0[8], a1[8];
  #pragma unroll
  for (int r = 0; r < 8; ++r) { a0[r] = 0.f; a1[r] = 0.f; }
  const float* Wo = W_out + (size_t)h * DM * DM;
  for (int p4 = 0; p4 < DM / 4; ++p4) {
    float m0[4], m1[4];
    #pragma unroll
    for (int u = 0; u < 4; ++u) {
      m0[u] = Wo[(size_t)(p4 * 4 + u) * DM + tid];
      m1[u] = Wo[(size_t)(p4 * 4 + u) * DM + tid + 256];
    }
    #pragma unroll
    for (int r = 0; r < 8; ++r) {
      float4 c4 = sWv4[r][p4];
      a0[r] = fmaf(c4.x, m0[0], a0[r]); a0[r] = fmaf(c4.y, m0[1], a0[r]);
      a0[r] = fmaf(c4.z, m0[2], a0[r]); a0[r] = fmaf(c4.w, m0[3], a0[r]);
      a1[r] = fmaf(c4.x, m1[0], a1[r]); a1[r] = fmaf(c4.y, m1[1], a1[r]);
      a1[r] = fmaf(c4.z, m1[2], a1[r]); a1[r] = fmaf(c4.w, m1[3], a1[r]);
    }
  }
  #pragma unroll
  for (int r = 0; r < 8; ++r) {
    size_t row = (size_t)h * DK + d0 + r;
    M2[row * DM + tid] = a0[r];
    M2[row * DM + tid + 256] = a1[r];
  }
}

// ===== K4: fused phi_q (+q-codes) / phi_k. 64 rows/block. grid (BL/64, NH, 2) =====
// omega[h] staged in LDS (fetched once/block); phi written with nontemporal
// stores (write-once stream must not thrash L2 operand residency).
__global__ __launch_bounds__(256, 2) void k_phi(
    const float* __restrict__ qd, const float* __restrict__ kd,
    const float* __restrict__ WabsT,
    const float* __restrict__ omega, const float* __restrict__ rff_bias,
    float* __restrict__ phiq, float* __restrict__ phik,
    u64* __restrict__ qcodes8) {
  int r0 = blockIdx.x * 64;
  int h = blockIdx.y;
  int isK = blockIdx.z;
  int tid = threadIdx.x;
  __shared__ float som[DK][RFF];   // 32KB omega[h], [d][col]
  __shared__ float qp[64][DK];     // 16KB projected/staged rows
  __shared__ float sq[64][DK];     // 16KB raw q rows (q path only)

  // stage omega[h]: 8192 floats = 2048 float4
  const float4* og = (const float4*)(omega + (size_t)h * DK * RFF);
  float4* o4 = (float4*)&som[0][0];
  #pragma unroll
  for (int u = 0; u < 8; ++u) o4[tid + u * 256] = og[tid + u * 256];

  if (!isK) {
    const float4* g4 = (const float4*)(qd + (size_t)r0 * DK);
    float4* l4 = (float4*)&sq[0][0];
    #pragma unroll
    for (int u = 0; u < 4; ++u) l4[tid + u * 256] = g4[tid + u * 256];
    __syncthreads();
    // Qp: wave wv computes rows wv*16..wv*16+15; lane = output dim a_
    int a_ = tid & 63, wv = tid >> 6;
    float acc[16];
    #pragma unroll
    for (int r = 0; r < 16; ++r) acc[r] = 0.f;
    const float* Wt = WabsT + h * DK * DK;
    for (int t = 0; t < DK; ++t) {
      float w = Wt[t * DK + a_];         // global, L1/L2-resident (16KB/head)
      #pragma unroll
      for (int r = 0; r < 16; ++r) acc[r] = fmaf(sq[wv * 16 + r][t], w, acc[r]);
    }
    #pragma unroll
    for (int r = 0; r < 16; ++r) {
      u64 m = __ballot(acc[r] > 0.f);    // bit a_ = sign of Qp dim a_
      int R = r0 + wv * 16 + r;
      if (a_ == 0) {
        int b = R >> 11, i = R & 2047;
        qcodes8[(((size_t)h * BB + b) << 11) + i] = m;
      }
      qp[wv * 16 + r][a_] = acc[r];
    }
    __syncthreads();
  } else {
    const float4* g4 = (const float4*)(kd + (size_t)r0 * DK);
    float4* l4 = (float4*)&qp[0][0];
    #pragma unroll
    for (int u = 0; u < 4; ++u) l4[tid + u * 256] = g4[tid + u * 256];
    __syncthreads();
  }

  // RFF: col = tid&127, half = tid>>7 -> 32 rows per thread
  int col = tid & 127, half = tid >> 7;
  float bias = rff_bias[h * RFF + col];
  float acc2[32];
  #pragma unroll
  for (int r = 0; r < 32; ++r) acc2[r] = bias;
  for (int d4 = 0; d4 < DK / 4; ++d4) {
    float w[4];
    #pragma unroll
    for (int u = 0; u < 4; ++u) w[u] = som[d4 * 4 + u][col];  // lanes consec: free
    #pragma unroll
    for (int r = 0; r < 32; ++r) {
      float4 qv = *(const float4*)&qp[half * 32 + r][d4 * 4]; // b128 broadcast
      acc2[r] = fmaf(qv.x, w[0], acc2[r]); acc2[r] = fmaf(qv.y, w[1], acc2[r]);
      acc2[r] = fmaf(qv.z, w[2], acc2[r]); acc2[r] = fmaf(qv.w, w[3], acc2[r]);
    }
  }
  float* dst = (isK ? phik : phiq) +
               ((size_t)h * BL + r0 + half * 32) * RFF + col;
  #pragma unroll
  for (int r = 0; r < 32; ++r)
    __builtin_nontemporal_store(cosf(acc2[r]) * RFF_SCALE, dst + (size_t)r * RFF);
}

// ===== K5a: per-chunk histogram. grid (16 bg, 16 ch), block 256 (thread = code) =====
__global__ __launch_bounds__(256) void k_bhist(
    const unsigned char* __restrict__ kcodes, int* __restrict__ chist) {
  int bg = blockIdx.x, ch = blockIdx.y;
  int c = threadIdx.x;
  __shared__ unsigned int wrd[CHW / 4];
  if (c < CHW / 4)
    wrd[c] = ((const unsigned int*)(kcodes + (size_t)bg * LL + ch * CHW))[c];
  __syncthreads();
  unsigned int pat = (unsigned)c * 0x01010101u;
  int cnt = 0;
  #pragma unroll
  for (int t = 0; t < CHW / 4; ++t)
    cnt += __popc(zbytes(wrd[t] ^ pat));
  chist[((size_t)bg * NCH + ch) * 256 + c] = cnt;
}

// ===== K5b: exclusive scan over chunks (in-place) + clamped bcnt. grid 16 =====
__global__ __launch_bounds__(256) void k_bscan(
    int* __restrict__ chist, int* __restrict__ bcnt) {
  int bg = blockIdx.x, c = threadIdx.x;
  int base = 0;
  #pragma unroll
  for (int ch = 0; ch < NCH; ++ch) {
    size_t idx = ((size_t)bg * NCH + ch) * 256 + c;
    int v = chist[idx];
    chist[idx] = base;
    base += v;
  }
  bcnt[bg * 256 + c] = base < KMAX ? base : KMAX;
}

// ===== K5c: ordered scatter of first-KMAX indices. grid (16,16), block 256 =====
__global__ __launch_bounds__(256) void k_bscatter(
    const unsigned char* __restrict__ kcodes, const int* __restrict__ chist,
    int* __restrict__ bidx) {
  int bg = blockIdx.x, ch = blockIdx.y;
  int c = threadIdx.x;
  __shared__ unsigned int wrd[CHW / 4];
  if (c < CHW / 4)
    wrd[c] = ((const unsigned int*)(kcodes + (size_t)bg * LL + ch * CHW))[c];
  __syncthreads();
  int pos = chist[((size_t)bg * NCH + ch) * 256 + c];
  if (pos >= KMAX) return;
  unsigned int pat = (unsigned)c * 0x01010101u;
  int* out = bidx + ((size_t)bg * 256 + c) * KMAX;
  int j0 = ch * CHW;
  for (int t = 0; t < CHW / 4; ++t) {
    unsigned int zm = zbytes(wrd[t] ^ pat);
    while (zm) {
      int byte = (__ffs(zm) - 1) >> 3;       // lowest matching byte -> ascending j
      out[pos++] = j0 + t * 4 + byte;
      if (pos >= KMAX) return;
      zm &= zm - 1;
    }
  }
}

// ===== K6: FUSED candidates (bucket-list bitmap union) + scores + softmax + PV =====
// grid NQ/4 (XCD-chunk-swizzled), block 256 = 4 waves, one query per wave.
__global__ __launch_bounds__(256) void k_attn(
    const u64* __restrict__ qcodes8, const int* __restrict__ bcnt,
    const int* __restrict__ bidx,
    const float* __restrict__ phiq, const float* __restrict__ phik,
    const float* __restrict__ vd, float* __restrict__ ctx) {
  __shared__ __align__(16) int   lcs[4][KMAX];   // candidate indices
  __shared__ __align__(16) float lw [4][KMAX];   // softmax weights
  __shared__ float        ssc[4][KMAX];          // raw scores
  __shared__ float4       sph[4][RFF / 4];       // phiq row per wave
  __shared__ unsigned int bm [4][64];            // 2048-bit bitmap, lane = word
  // XCD-chunked swizzle: XCD x owns contiguous query range -> its L2 holds
  // one head's phik (2MB) + vd (1MB).
  int swz = (blockIdx.x & 7) * ((NQ / 4) / 8) + (blockIdx.x >> 3);
  int lane = threadIdx.x & 63;
  int wv = threadIdx.x >> 6;
  int qidx = swz * 4 + wv;
  int h = qidx >> 12;
  int b = (qidx >> 11) & 1;
  int i = qidx & 2047;
  int base = qidx - i;                 // (h*BB+b)*LL in phi-row space

  // ---- Phase A: union of 8 bucket lists via LDS bitmap (wave-local) ----
  lcs[wv][lane] = 0;
  bm[wv][lane] = 0u;
  u64 qc = qcodes8[(((size_t)h * BB + b) << 11) + i];   // wave-uniform
  #pragma unroll
  for (int g = 0; g < 8; ++g) {
    int code = (int)((qc >> (8 * g)) & 255);
    int bk = ((b * 8 + g) << 8) + code;
    int cnt = bcnt[bk];
    if (lane < cnt) {
      int j = bidx[(size_t)bk * KMAX + lane];
      atomicOr(&bm[wv][j >> 5], 1u << (j & 31));
    }
  }
  unsigned int wbits = bm[wv][lane];    // after all ds_or of this wave (program order)
  int cw = __popc(wbits);
  int pre = cw;                          // inclusive prefix sum over lanes
  #pragma unroll
  for (int off = 1; off < 64; off <<= 1) {
    int t = __shfl_up(pre, off);
    if (lane >= off) pre += t;
  }
  int total = __shfl(pre, 63);
  int nv = total < KMAX ? total : KMAX;
  int pos = pre - cw;                    // exclusive base for this word
  while (wbits && pos < KMAX) {
    int bit = __ffs(wbits) - 1;
    wbits &= wbits - 1;
    lcs[wv][pos++] = (lane << 5) + bit;  // ascending global order, cut at 64
  }

  // ---- Phase B: stage this query's phiq row (512B) ----
  if (lane < RFF / 4)
    sph[wv][lane] = ((const float4*)(phiq + (size_t)qidx * RFF))[lane];

  // ---- Phase C: scores, 4 lanes per candidate (coalesced 64B per candidate) ----
  int k16 = lane >> 2, f = lane & 3;
  #pragma unroll
  for (int cb = 0; cb < 4; ++cb) {
    int cd = cb * 16 + k16;
    int col = lcs[wv][cd];
    const float4* rp = (const float4*)(phik + (size_t)(base + col) * RFF);
    float p = 0.f;
    #pragma unroll
    for (int t = 0; t < 8; ++t) {
      int idx = t * 4 + f;
      float4 kv = rp[idx];           // lanes 4k..4k+3: one 64B granule of row
      float4 qv = sph[wv][idx];      // 16-way same-address broadcast
      p += kv.x * qv.x + kv.y * qv.y + kv.z * qv.z + kv.w * qv.w;
    }
    p += __shfl_xor(p, 1);
    p += __shfl_xor(p, 2);           // all 4 lanes hold the full dot
    if (f == 0) ssc[wv][cd] = p * INV_SQRT_RFF;
  }

  // ---- Phase D: softmax over the 64 slots (wave-local LDS exchange) ----
  float s = (lane < nv) ? ssc[wv][lane] : -1e30f;
  float m = s;
  #pragma unroll
  for (int off = 32; off >= 1; off >>= 1) m = fmaxf(m, __shfl_xor(m, off));
  float e = expf(s - m);
  float sum = e;
  #pragma unroll
  for (int off = 32; off >= 1; off >>= 1) sum += __shfl_xor(sum, off);
  float w_ = (lane < nv) ? (e / sum) : 0.f;
  lw[wv][lane] = w_;

  // ---- Phase E: weighted V accumulate (lane = d; vb rows coalesced 256B) ----
  float acc = 0.f;
  const float* vb = vd + (size_t)b * LL * DK;
  for (int k4 = 0; k4 < KMAX / 4; ++k4) {
    float4 w4 = *(const float4*)&lw[wv][k4 * 4];   // broadcast
    int4   c4 = *(const int4*)&lcs[wv][k4 * 4];
    acc = fmaf(w4.x, vb[(size_t)c4.x * DK + lane], acc);
    acc = fmaf(w4.y, vb[(size_t)c4.y * DK + lane], acc);
    acc = fmaf(w4.z, vb[(size_t)c4.z * DK + lane], acc);
    acc = fmaf(w4.w, vb[(size_t)c4.w * DK + lane], acc);
  }
  ctx[((size_t)(b * LL + i)) * (NH * DK) + h * DK + lane] = acc;
}

// ===== K8: out = ctx @ M2 + b_out, 16 rows/block. grid BL/16 =====
__global__ __launch_bounds__(256) void k_out(
    const float* __restrict__ ctx, const float* __restrict__ M2,
    const float* __restrict__ b_out, float* __restrict__ out) {
  int r0 = blockIdx.x * 16;
  int tid = threadIdx.x;
  __shared__ float4 sctx4[16][DM / 4];
  const float4* g4 = (const float4*)(ctx + (size_t)r0 * DM);
  float4* l4 = &sctx4[0][0];
  #pragma unroll
  for (int u = 0; u < 8; ++u) l4[tid + u * 256] = g4[tid + u * 256];
  __syncthreads();
  float a0[16], a1[16];
  #pragma unroll
  for (int r = 0; r < 16; ++r) { a0[r] = 0.f; a1[r] = 0.f; }
  for (int p4 = 0; p4 < DM / 4; ++p4) {
    float m0[4], m1[4];
    #pragma unroll
    for (int u = 0; u < 4; ++u) {
      m0[u] = M2[(size_t)(p4 * 4 + u) * DM + tid];
      m1[u] = M2[(size_t)(p4 * 4 + u) * DM + tid + 256];
    }
    #pragma unroll
    for (int r = 0; r < 16; ++r) {
      float4 c4 = sctx4[r][p4];
      a0[r] = fmaf(c4.x, m0[0], a0[r]); a0[r] = fmaf(c4.y, m0[1], a0[r]);
      a0[r] = fmaf(c4.z, m0[2], a0[r]); a0[r] = fmaf(c4.w, m0[3], a0[r]);
      a1[r] = fmaf(c4.x, m1[0], a1[r]); a1[r] = fmaf(c4.y, m1[1], a1[r]);
      a1[r] = fmaf(c4.z, m1[2], a1[r]); a1[r] = fmaf(c4.w, m1[3], a1[r]);
    }
  }
  float b0 = b_out[tid], b1 = b_out[tid + 256];
  #pragma unroll
  for (int r = 0; r < 16; ++r) {
    out[(size_t)(r0 + r) * DM + tid] = a0[r] + b0;
    out[(size_t)(r0 + r) * DM + tid + 256] = a1[r] + b1;
  }
}

extern "C" void kernel_launch(void* const* d_in, const int* in_sizes, int n_in,
                              void* d_out, int out_size, void* d_ws, size_t ws_size,
                              hipStream_t stream) {
  const float* query = (const float*)d_in[0];
  const float* key   = (const float*)d_in[1];
  const float* value = (const float*)d_in[2];
  const float* Wq    = (const float*)d_in[3];
  const float* bq    = (const float*)d_in[4];
  const float* Wkv   = (const float*)d_in[5];
  const float* bkv   = (const float*)d_in[6];
  const float* u_q   = (const float*)d_in[7];
  const float* v_q   = (const float*)d_in[8];
  const float* u_k   = (const float*)d_in[9];
  const float* v_k   = (const float*)d_in[10];
  const float* u_v   = (const float*)d_in[11];
  const float* v_v   = (const float*)d_in[12];
  const float* omega = (const float*)d_in[13];
  const float* rffb  = (const float*)d_in[14];
  const float* W_out = (const float*)d_in[15];
  const float* b_out = (const float*)d_in[16];
  float* out = (float*)d_out;

  // ---- workspace carve (256B aligned) ----
  size_t off = 0;
  char* ws = (char*)d_ws;
  auto carve = [&](size_t bytes) -> void* {
    void* p = ws + off;
    off += (bytes + 255) & ~(size_t)255;
    return p;
  };
  float* qd    = (float*)carve((size_t)BL * DK * 4);
  float* kd    = (float*)carve((size_t)BL * DK * 4);
  float* vd    = (float*)carve((size_t)BL * DK * 4);
  float* WabsT = (float*)carve((size_t)NH * DK * DK * 4);
  float* Wv    = (float*)carve((size_t)NH * DK * DM * 4);
  float* M2    = (float*)carve((size_t)NH * DK * DM * 4);
  float* phiq  = (float*)carve((size_t)NQ * RFF * 4);
  float* phik  = (float*)carve((size_t)NQ * RFF * 4);
  unsigned char* kcodes = (unsigned char*)carve((size_t)BB * 8 * LL);
  u64* qcodes8 = (u64*)carve((size_t)NH * BB * LL * 8);
  int* chist = (int*)carve((size_t)BB * 8 * NCH * 256 * 4);
  int* bcnt  = (int*)carve((size_t)BB * 8 * 256 * 4);
  int* bidx  = (int*)carve((size_t)BB * 8 * 256 * KMAX * 4);
  float* ctx = (float*)carve((size_t)BL * NH * DK * 4);
  (void)ws_size;

  // ---- launches (fixed sequence, all on stream) ----
  k_down_proj<<<dim3(BL / 16, 3), 256, 0, stream>>>(query, key, value, Wq, bq, Wkv, bkv,
                                                    qd, kd, vd, kcodes);
  k_head_pre<<<NH, 256, 0, stream>>>(u_q, v_q, u_k, v_k, u_v, v_v, WabsT, Wv);
  k_m2<<<dim3(NH, 8), 256, 0, stream>>>(Wv, W_out, M2);
  k_phi<<<dim3(BL / 64, NH, 2), 256, 0, stream>>>(qd, kd, WabsT, omega, rffb,
                                                  phiq, phik, qcodes8);
  k_bhist<<<dim3(BB * 8, NCH), 256, 0, stream>>>(kcodes, chist);
  k_bscan<<<BB * 8, 256, 0, stream>>>(chist, bcnt);
  k_bscatter<<<dim3(BB * 8, NCH), 256, 0, stream>>>(kcodes, chist, bidx);
  k_attn<<<NQ / 4, 256, 0, stream>>>(qcodes8, bcnt, bidx, phiq, phik, vd, ctx);
  k_out<<<BL / 16, 256, 0, stream>>>(ctx, M2, b_out, out);
}